// Round 8
// baseline (125.621 us; speedup 1.0000x reference)
//
#include <hip/hip_runtime.h>
#include <stdint.h>

#define L_DIM 16384
#define H_DIM 512
#define P_DIM 512
#define T_CH  32
#define NC    (L_DIM / T_CH)      // 512 chunks
#define LP    ((size_t)L_DIM * P_DIM)
#define LH    ((size_t)L_DIM * H_DIM)

typedef unsigned short u16;
typedef __attribute__((ext_vector_type(8))) _Float16 f16x8;  // 8 fp16 = 4 VGPRs
typedef __attribute__((ext_vector_type(4))) float f32x4;
typedef __attribute__((ext_vector_type(8))) unsigned short u16x8;

// ---- fp16 helpers ----------------------------------------------------------
__device__ __forceinline__ u16 f2h(float x) {
    _Float16 h = (_Float16)x;            // RTNE
    return __builtin_bit_cast(u16, h);
}
__device__ __forceinline__ float h2f(u16 h) {
    return (float)__builtin_bit_cast(_Float16, h);
}

// ---- async global->LDS, 16B per lane, wave-uniform LDS base ----------------
__device__ __forceinline__ void gload16(const void* g, void* lds) {
    __builtin_amdgcn_global_load_lds(
        (const __attribute__((address_space(1))) void*)g,
        (__attribute__((address_space(3))) void*)(uintptr_t)lds,
        16, 0, 0);
}

__device__ __forceinline__ f32x4 mfma_f16(f16x8 a, f16x8 b, f32x4 c) {
    return __builtin_amdgcn_mfma_f32_16x16x32_f16(a, b, c, 0, 0, 0);
}

// ---------------------------------------------------------------------------
// front kernel: one dispatch = convert_u + Bcat + Ccat + lambda/power prep.
// ---------------------------------------------------------------------------
__device__ __forceinline__ void zoh_lambda(
    const float* Lre, const float* Lim, const float* log_step, int p,
    float& lr, float& li)
{
    float st = expf(log_step[p]);
    float ar = Lre[p] * st, ai = Lim[p] * st;
    float er = expf(ar);
    lr = er * cosf(ai);
    li = er * sinf(ai);
}

__global__ __launch_bounds__(256) void front_kernel(
    const float* __restrict__ u,
    const float* __restrict__ Lre, const float* __restrict__ Lim,
    const float* __restrict__ log_step,
    const float* __restrict__ Bre, const float* __restrict__ Bim,
    const float* __restrict__ Cre, const float* __restrict__ Cim,
    u16* __restrict__ uh, u16* __restrict__ Bcat, u16* __restrict__ Ccat,
    float* __restrict__ lbr, float* __restrict__ lbi,
    float* __restrict__ powr, float* __restrict__ powi)
{
    int b = blockIdx.x;
    if (b < 4096) {
        size_t i = ((size_t)b * 256 + threadIdx.x) * 8;
        float4 v0 = *(const float4*)(u + i);
        float4 v1 = *(const float4*)(u + i + 4);
        u16x8 h;
        h[0] = f2h(v0.x); h[1] = f2h(v0.y); h[2] = f2h(v0.z); h[3] = f2h(v0.w);
        h[4] = f2h(v1.x); h[5] = f2h(v1.y); h[6] = f2h(v1.z); h[7] = f2h(v1.w);
        *(u16x8*)(uh + i) = h;
    } else if (b < 5120) {
        int idx = (b - 4096) * 256 + threadIdx.x;   // p*H + h
        int p = idx >> 9, h = idx & 511;
        float lr, li;
        zoh_lambda(Lre, Lim, log_step, p, lr, li);
        float den = Lre[p] * Lre[p] + Lim[p] * Lim[p];
        float x = lr - 1.0f, y = li;
        float gr = (x * Lre[p] + y * Lim[p]) / den;
        float gi = (y * Lre[p] - x * Lim[p]) / den;
        float br = Bre[idx], bi = Bim[idx];
        Bcat[(size_t)p * 512 + h]         = f2h(gr * br - gi * bi);
        Bcat[(size_t)(512 + p) * 512 + h] = f2h(gr * bi + gi * br);
    } else if (b < 6144) {
        int idx = (b - 5120) * 256 + threadIdx.x;   // h*P + p
        int h = idx >> 9, p = idx & 511;
        size_t row = (size_t)h * 1024;
        Ccat[row + p]       = f2h(Cre[idx]);
        Ccat[row + 512 + p] = f2h(-Cim[idx]);
    } else {
        #pragma unroll
        for (int t = 0; t < 2; ++t) {
            int p = threadIdx.x + t * 256;
            float lr, li;
            zoh_lambda(Lre, Lim, log_step, p, lr, li);
            lbr[p] = lr; lbi[p] = li;
            float pr = 1.f, pi2 = 0.f;
            powr[p] = 1.f; powi[p] = 0.f;
            for (int k = 1; k <= T_CH; ++k) {
                float nr = pr * lr - pi2 * li;
                float ni = pr * li + pi2 * lr;
                pr = nr; pi2 = ni;
                powr[(size_t)k * P_DIM + p] = pr;
                powi[(size_t)k * P_DIM + p] = pi2;
            }
        }
    }
}

// ---------------------------------------------------------------------------
// Bu GEMM: 128x128 tile, BK=64, 4 waves, global_load_lds staging with
// XOR-swizzled source / ds_read pair. Writes Bu fp16 (re|im split at col 512)
// AND fused weighted chunk-sum partials from the fp32 accumulators
// (w_k = lambda_p^(31-k)).
// __launch_bounds__(256,2): 256-reg budget. (256,4) caps at 128 and SPILLS —
// round-3 regression: +183MB scratch writes/dispatch, GEMM 64->118us.
// ---------------------------------------------------------------------------
__global__ __launch_bounds__(256, 2) void gemm_bu(
    const u16* __restrict__ A0,
    const u16* __restrict__ Bmat,
    u16* __restrict__ O0, u16* __restrict__ O1,
    const float* __restrict__ powr, const float* __restrict__ powi,
    float* __restrict__ Rwr, float* __restrict__ Rwi,
    float* __restrict__ Iwr, float* __restrict__ Iwi)
{
    const int NBN = 8;
    __shared__ u16 Als[128 * 64];
    __shared__ u16 Bls[128 * 64];

    int b = blockIdx.x;
    int m = (b & 7) * 16 + b / (8 * NBN);
    int n = (b >> 3) & (NBN - 1);
    int m0 = m * 128, n0 = n * 128;

    int tid = threadIdx.x;
    int w = tid >> 6, lane = tid & 63;
    int wm = w >> 1, wn = w & 1;

    f32x4 acc[4][4];
    #pragma unroll
    for (int i = 0; i < 4; ++i)
        #pragma unroll
        for (int j = 0; j < 4; ++j) acc[i][j] = (f32x4)0.f;

    int lr8  = lane >> 3;
    int slin = lane & 7;

    char* AlsB = (char*)&Als[0];
    char* BlsB = (char*)&Bls[0];

    for (int k8 = 0; k8 < 8; ++k8) {
        int ko = k8 * 64;

        __syncthreads();
        #pragma unroll
        for (int c = 0; c < 4; ++c) {
            int sidx = w * 4 + c;
            int r = sidx * 8 + lr8;
            int g = slin ^ (r & 7);
            gload16(A0   + (size_t)(m0 + r) * 512 + ko + g * 8, AlsB + sidx * 1024);
            gload16(Bmat + (size_t)(n0 + r) * 512 + ko + g * 8, BlsB + sidx * 1024);
        }
        asm volatile("s_waitcnt vmcnt(0)" ::: "memory");
        __syncthreads();

        f16x8 a[4][2], bf[4][2];
        #pragma unroll
        for (int mm = 0; mm < 4; ++mm)
            #pragma unroll
            for (int kk = 0; kk < 2; ++kk) {
                int row = wm * 64 + mm * 16 + (lane & 15);
                int sl  = kk * 4 + (lane >> 4);
                int off = row * 128 + ((sl ^ (lane & 7)) << 4);
                a[mm][kk] = *(const f16x8*)(AlsB + off);
            }
        #pragma unroll
        for (int nn = 0; nn < 4; ++nn)
            #pragma unroll
            for (int kk = 0; kk < 2; ++kk) {
                int row = wn * 64 + nn * 16 + (lane & 15);
                int sl  = kk * 4 + (lane >> 4);
                int off = row * 128 + ((sl ^ (lane & 7)) << 4);
                bf[nn][kk] = *(const f16x8*)(BlsB + off);
            }
        #pragma unroll
        for (int mm = 0; mm < 4; ++mm)
            #pragma unroll
            for (int nn = 0; nn < 4; ++nn) {
                acc[mm][nn] = mfma_f16(a[mm][0], bf[nn][0], acc[mm][nn]);
                acc[mm][nn] = mfma_f16(a[mm][1], bf[nn][1], acc[mm][nn]);
            }
    }

    // epilogue: C/D layout col = lane&15, row = (lane>>4)*4 + reg  [m89]
    int colb = n0 + wn * 64;
    int rowb = m0 + wm * 64;
    #pragma unroll
    for (int mm = 0; mm < 4; ++mm)
        #pragma unroll
        for (int nn = 0; nn < 4; ++nn) {
            f32x4 v = acc[mm][nn];
            int col = colb + nn * 16 + (lane & 15);
            #pragma unroll
            for (int j = 0; j < 4; ++j) {
                int row = rowb + mm * 16 + (lane >> 4) * 4 + j;
                size_t oidx = (size_t)row * 512 + (col & 511);
                u16 hv = f2h(v[j]);
                if (col < 512) O0[oidx] = hv;
                else           O1[oidx] = hv;
            }
        }

    // fused weighted chunk sums (64 weight loads/lane; k depends on (mm&1,j))
    float swr[2][4] = {{0.f}};
    float swi[2][4] = {{0.f}};
    #pragma unroll
    for (int h = 0; h < 2; ++h)
        #pragma unroll
        for (int j = 0; j < 4; ++j) {
            int k = h * 16 + (lane >> 4) * 4 + j;    // 0..31
            int e = (T_CH - 1) - k;
            #pragma unroll
            for (int nn = 0; nn < 4; ++nn) {
                int p = (colb + nn * 16 + (lane & 15)) & 511;
                float wr = powr[(size_t)e * 512 + p];
                float wi = powi[(size_t)e * 512 + p];
                swr[0][nn] = fmaf(wr, acc[h][nn][j],     swr[0][nn]);
                swi[0][nn] = fmaf(wi, acc[h][nn][j],     swi[0][nn]);
                swr[1][nn] = fmaf(wr, acc[2 + h][nn][j], swr[1][nn]);
                swi[1][nn] = fmaf(wi, acc[2 + h][nn][j], swi[1][nn]);
            }
        }
    #pragma unroll
    for (int ch = 0; ch < 2; ++ch)
        #pragma unroll
        for (int nn = 0; nn < 4; ++nn) {
            float a2 = swr[ch][nn];
            a2 += __shfl_xor(a2, 16); a2 += __shfl_xor(a2, 32);
            swr[ch][nn] = a2;
            float b2 = swi[ch][nn];
            b2 += __shfl_xor(b2, 16); b2 += __shfl_xor(b2, 32);
            swi[ch][nn] = b2;
        }
    if (lane < 16) {
        #pragma unroll
        for (int ch = 0; ch < 2; ++ch) {
            int c = (m0 >> 5) + wm * 2 + ch;
            #pragma unroll
            for (int nn = 0; nn < 4; ++nn) {
                int col = colb + nn * 16 + lane;
                int p = col & 511;
                size_t pidx = (size_t)c * 512 + p;
                if (col < 512) { Rwr[pidx] = swr[ch][nn]; Rwi[pidx] = swi[ch][nn]; }
                else           { Iwr[pidx] = swr[ch][nn]; Iwi[pidx] = swi[ch][nn]; }
            }
        }
    }
}

// ---------------------------------------------------------------------------
// scan chunks: exclusive scan across 512 chunk aggregates with factor
// lambda^32, combining partials: s_re = Rwr - Iwi ; s_im = Rwi + Iwr.
// 8 blocks x 64 threads so L2 traffic isn't funneled through one CU.
// ---------------------------------------------------------------------------
__global__ __launch_bounds__(64) void scan_chunks(
    const float* __restrict__ Rwr, const float* __restrict__ Rwi,
    const float* __restrict__ Iwr, const float* __restrict__ Iwi,
    const float* __restrict__ powr, const float* __restrict__ powi,
    float* __restrict__ carr, float* __restrict__ cari)
{
    int p = blockIdx.x * 64 + threadIdx.x;
    float ar = powr[(size_t)T_CH * P_DIM + p];   // lambda^32
    float ai = powi[(size_t)T_CH * P_DIM + p];
    float sr = 0.f, si = 0.f;
    #pragma unroll 8
    for (int c = 0; c < NC; ++c) {
        size_t idx = (size_t)c * P_DIM + p;
        carr[idx] = sr; cari[idx] = si;
        float vre = Rwr[idx] - Iwi[idx];
        float vim = Rwi[idx] + Iwr[idx];
        float nr = fmaf(ar, sr, fmaf(-ai, si, vre));
        float ni = fmaf(ar, si, fmaf( ai, sr, vim));
        sr = nr; si = ni;
    }
}

// ---------------------------------------------------------------------------
// y GEMM with FUSED scan_fix: the A-operand x is computed on the fly from
// Bu + per-chunk carries (removes the 67MB x round-trip through HBM and one
// dispatch). K=1024 = [xr | xi] processed in PAIRS (q, q+8) so the complex
// recurrence per channel-group runs once: 256 threads = 4 chunks x 64
// channels, each a serial 32-step chain from carr/cari, results written fp16
// into the XOR-swizzled LDS A-tiles (ds_write_b16: 64 lanes x consecutive 2B
// = conflict-free). Both halves accumulate into the same acc (K-concat).
// out = acc + D[col]*uh. Numerically identical to scan_fix+gemm path.
// ---------------------------------------------------------------------------
__global__ __launch_bounds__(256, 2) void gemm_y_fused(
    const u16* __restrict__ burh, const u16* __restrict__ buih,
    const u16* __restrict__ Ccat,
    const float* __restrict__ lbr, const float* __restrict__ lbi,
    const float* __restrict__ carr, const float* __restrict__ cari,
    const float* __restrict__ Dvec, const u16* __restrict__ uIn,
    float* __restrict__ out)
{
    __shared__ u16 Axr[128 * 64];
    __shared__ u16 Axi[128 * 64];
    __shared__ u16 Bl0[128 * 64];
    __shared__ u16 Bl1[128 * 64];

    int b = blockIdx.x;
    int m = (b & 7) * 16 + b / 32;      // NBN=4
    int n = (b >> 3) & 3;
    int m0 = m * 128, n0 = n * 128;

    int tid = threadIdx.x;
    int w = tid >> 6, lane = tid & 63;
    int wm = w >> 1, wn = w & 1;

    f32x4 acc[4][4];
    #pragma unroll
    for (int i = 0; i < 4; ++i)
        #pragma unroll
        for (int j = 0; j < 4; ++j) acc[i][j] = (f32x4)0.f;

    int lr8  = lane >> 3;
    int slin = lane & 7;

    char* AxrB = (char*)&Axr[0];
    char* AxiB = (char*)&Axi[0];
    char* B0B  = (char*)&Bl0[0];
    char* B1B  = (char*)&Bl1[0];

    // x-compute mapping: wave = chunk, lane = channel-in-group
    int ch = w;                  // chunk 0..3 within tile
    int cglob = m * 4 + ch;      // global chunk

    for (int q = 0; q < 8; ++q) {
        int kB0 = q * 64;            // Ccat cols for xr half
        int kB1 = 512 + q * 64;      // Ccat cols for xi half

        __syncthreads();             // previous tiles fully consumed
        #pragma unroll
        for (int c = 0; c < 4; ++c) {
            int sidx = w * 4 + c;
            int r = sidx * 8 + lr8;
            int g = slin ^ (r & 7);
            gload16(Ccat + (size_t)(n0 + r) * 1024 + kB0 + g * 8, B0B + sidx * 1024);
            gload16(Ccat + (size_t)(n0 + r) * 1024 + kB1 + g * 8, B1B + sidx * 1024);
        }

        // compute x for channels p = q*64+lane, 32 rows of this wave's chunk
        {
            int p = q * 64 + lane;
            float lr_ = lbr[p], li_ = lbi[p];
            float xr = carr[(size_t)cglob * 512 + p];
            float xi = cari[(size_t)cglob * 512 + p];
            size_t gbase = (size_t)(m0 + ch * 32) * 512 + p;
            int rloc = ch * 32;
            int gsel = lane >> 3;            // granule of this channel
            int boff = (lane & 7) * 2;       // byte within granule
            #pragma unroll 4
            for (int k = 0; k < 32; ++k) {
                float br = h2f(burh[gbase + (size_t)k * 512]);
                float bi = h2f(buih[gbase + (size_t)k * 512]);
                float nr = fmaf(lr_, xr, fmaf(-li_, xi, br));
                float ni = fmaf(lr_, xi, fmaf( li_, xr, bi));
                xr = nr; xi = ni;
                int r = rloc + k;
                int off = r * 128 + ((gsel ^ (r & 7)) << 4) + boff;
                *(u16*)(AxrB + off) = f2h(nr);
                *(u16*)(AxiB + off) = f2h(ni);
            }
        }
        asm volatile("s_waitcnt vmcnt(0)" ::: "memory");
        __syncthreads();             // staged tiles visible

        // half 0: xr x Cre-part
        {
            f16x8 a[4][2], bf[4][2];
            #pragma unroll
            for (int mm = 0; mm < 4; ++mm)
                #pragma unroll
                for (int kk = 0; kk < 2; ++kk) {
                    int row = wm * 64 + mm * 16 + (lane & 15);
                    int sl  = kk * 4 + (lane >> 4);
                    int off = row * 128 + ((sl ^ (lane & 7)) << 4);
                    a[mm][kk] = *(const f16x8*)(AxrB + off);
                }
            #pragma unroll
            for (int nn = 0; nn < 4; ++nn)
                #pragma unroll
                for (int kk = 0; kk < 2; ++kk) {
                    int row = wn * 64 + nn * 16 + (lane & 15);
                    int sl  = kk * 4 + (lane >> 4);
                    int off = row * 128 + ((sl ^ (lane & 7)) << 4);
                    bf[nn][kk] = *(const f16x8*)(B0B + off);
                }
            #pragma unroll
            for (int mm = 0; mm < 4; ++mm)
                #pragma unroll
                for (int nn = 0; nn < 4; ++nn) {
                    acc[mm][nn] = mfma_f16(a[mm][0], bf[nn][0], acc[mm][nn]);
                    acc[mm][nn] = mfma_f16(a[mm][1], bf[nn][1], acc[mm][nn]);
                }
        }
        // half 1: xi x (-Cim)-part
        {
            f16x8 a[4][2], bf[4][2];
            #pragma unroll
            for (int mm = 0; mm < 4; ++mm)
                #pragma unroll
                for (int kk = 0; kk < 2; ++kk) {
                    int row = wm * 64 + mm * 16 + (lane & 15);
                    int sl  = kk * 4 + (lane >> 4);
                    int off = row * 128 + ((sl ^ (lane & 7)) << 4);
                    a[mm][kk] = *(const f16x8*)(AxiB + off);
                }
            #pragma unroll
            for (int nn = 0; nn < 4; ++nn)
                #pragma unroll
                for (int kk = 0; kk < 2; ++kk) {
                    int row = wn * 64 + nn * 16 + (lane & 15);
                    int sl  = kk * 4 + (lane >> 4);
                    int off = row * 128 + ((sl ^ (lane & 7)) << 4);
                    bf[nn][kk] = *(const f16x8*)(B1B + off);
                }
            #pragma unroll
            for (int mm = 0; mm < 4; ++mm)
                #pragma unroll
                for (int nn = 0; nn < 4; ++nn) {
                    acc[mm][nn] = mfma_f16(a[mm][0], bf[nn][0], acc[mm][nn]);
                    acc[mm][nn] = mfma_f16(a[mm][1], bf[nn][1], acc[mm][nn]);
                }
        }
    }

    // epilogue: out = acc + D*u
    int colb = n0 + wn * 64;
    int rowb = m0 + wm * 64;
    #pragma unroll
    for (int mm = 0; mm < 4; ++mm)
        #pragma unroll
        for (int nn = 0; nn < 4; ++nn) {
            f32x4 v = acc[mm][nn];
            int col = colb + nn * 16 + (lane & 15);
            #pragma unroll
            for (int j = 0; j < 4; ++j) {
                int row = rowb + mm * 16 + (lane >> 4) * 4 + j;
                size_t oidx = (size_t)row * 512 + col;
                out[oidx] = v[j] + Dvec[col] * h2f(uIn[oidx]);
            }
        }
}

// ---------------------------------------------------------------------------
extern "C" void kernel_launch(void* const* d_in, const int* in_sizes, int n_in,
                              void* d_out, int out_size, void* d_ws, size_t ws_size,
                              hipStream_t stream)
{
    const float* u        = (const float*)d_in[0];
    const float* Lre      = (const float*)d_in[1];
    const float* Lim      = (const float*)d_in[2];
    const float* Bre      = (const float*)d_in[3];
    const float* Bim      = (const float*)d_in[4];
    const float* Cre      = (const float*)d_in[5];
    const float* Cim      = (const float*)d_in[6];
    const float* D        = (const float*)d_in[7];
    const float* log_step = (const float*)d_in[8];
    float* out = (float*)d_out;

    // workspace layout (bytes)
    char* w8 = (char*)d_ws;
    u16*   burh = (u16*)(w8);                                // 16 MB
    u16*   buih = (u16*)(w8 + 16777216);                     // 16 MB
    u16*   uh   = (u16*)(w8 + 33554432);                     // 16 MB
    u16*   Bcat = (u16*)(w8 + 50331648);                     // 1 MB
    u16*   Ccat = (u16*)(w8 + 51380224);                     // 1 MB
    float* Rwr  = (float*)(w8 + 52428800);                   // 1 MB (NC*P fp32)
    float* Rwi  = (float*)(w8 + 53477376);
    float* Iwr  = (float*)(w8 + 54525952);
    float* Iwi  = (float*)(w8 + 55574528);
    float* carr = (float*)(w8 + 56623104);                   // 1 MB
    float* cari = (float*)(w8 + 57671680);
    float* powr = (float*)(w8 + 58720256);                   // 33*512*4
    float* powi = (float*)(w8 + 58787840);
    float* lbr  = (float*)(w8 + 58855424);                   // small
    float* lbi  = lbr + P_DIM;

    // one front dispatch: convert_u (4096 blk) + Bcat (1024) + Ccat (1024)
    // + lambda/power prep (1 blk)
    front_kernel<<<6145, 256, 0, stream>>>(
        u, Lre, Lim, log_step, Bre, Bim, Cre, Cim,
        uh, Bcat, Ccat, lbr, lbi, powr, powi);

    // Bu GEMM (+fused chunk-sum partials): A = uh, B = Bcat (1024 x 512)
    gemm_bu<<<1024, 256, 0, stream>>>(
        uh, Bcat, burh, buih, powr, powi, Rwr, Rwi, Iwr, Iwi);

    scan_chunks<<<8, 64, 0, stream>>>(Rwr, Rwi, Iwr, Iwi, powr, powi, carr, cari);

    // y GEMM with fused scan_fix: x computed in-kernel from Bu + carries
    gemm_y_fused<<<512, 256, 0, stream>>>(
        burh, buih, Ccat, lbr, lbi, carr, cari, D, uh, out);
}

// Round 9
// 125.381 us; speedup vs baseline: 1.0019x; 1.0019x over previous
//
#include <hip/hip_runtime.h>
#include <stdint.h>

#define L_DIM 16384
#define H_DIM 512
#define P_DIM 512
#define T_CH  32
#define NC    (L_DIM / T_CH)      // 512 chunks
#define LP    ((size_t)L_DIM * P_DIM)
#define LH    ((size_t)L_DIM * H_DIM)

typedef unsigned short u16;
typedef __attribute__((ext_vector_type(8))) _Float16 f16x8;  // 8 fp16 = 4 VGPRs
typedef __attribute__((ext_vector_type(4))) float f32x4;
typedef __attribute__((ext_vector_type(8))) unsigned short u16x8;

// ---- fp16 helpers ----------------------------------------------------------
__device__ __forceinline__ u16 f2h(float x) {
    _Float16 h = (_Float16)x;            // RTNE
    return __builtin_bit_cast(u16, h);
}
__device__ __forceinline__ float h2f(u16 h) {
    return (float)__builtin_bit_cast(_Float16, h);
}

// ---- async global->LDS, 16B per lane, wave-uniform LDS base ----------------
__device__ __forceinline__ void gload16(const void* g, void* lds) {
    __builtin_amdgcn_global_load_lds(
        (const __attribute__((address_space(1))) void*)g,
        (__attribute__((address_space(3))) void*)(uintptr_t)lds,
        16, 0, 0);
}

__device__ __forceinline__ f32x4 mfma_f16(f16x8 a, f16x8 b, f32x4 c) {
    return __builtin_amdgcn_mfma_f32_16x16x32_f16(a, b, c, 0, 0, 0);
}

// ---------------------------------------------------------------------------
// front kernel: one dispatch = convert_u + Bcat + Ccat + lambda/power prep.
// ---------------------------------------------------------------------------
__device__ __forceinline__ void zoh_lambda(
    const float* Lre, const float* Lim, const float* log_step, int p,
    float& lr, float& li)
{
    float st = expf(log_step[p]);
    float ar = Lre[p] * st, ai = Lim[p] * st;
    float er = expf(ar);
    lr = er * cosf(ai);
    li = er * sinf(ai);
}

__global__ __launch_bounds__(256) void front_kernel(
    const float* __restrict__ u,
    const float* __restrict__ Lre, const float* __restrict__ Lim,
    const float* __restrict__ log_step,
    const float* __restrict__ Bre, const float* __restrict__ Bim,
    const float* __restrict__ Cre, const float* __restrict__ Cim,
    u16* __restrict__ uh, u16* __restrict__ Bcat, u16* __restrict__ Ccat,
    float* __restrict__ lbr, float* __restrict__ lbi,
    float* __restrict__ powr, float* __restrict__ powi)
{
    int b = blockIdx.x;
    if (b < 4096) {
        size_t i = ((size_t)b * 256 + threadIdx.x) * 8;
        float4 v0 = *(const float4*)(u + i);
        float4 v1 = *(const float4*)(u + i + 4);
        u16x8 h;
        h[0] = f2h(v0.x); h[1] = f2h(v0.y); h[2] = f2h(v0.z); h[3] = f2h(v0.w);
        h[4] = f2h(v1.x); h[5] = f2h(v1.y); h[6] = f2h(v1.z); h[7] = f2h(v1.w);
        *(u16x8*)(uh + i) = h;
    } else if (b < 5120) {
        int idx = (b - 4096) * 256 + threadIdx.x;   // p*H + h
        int p = idx >> 9, h = idx & 511;
        float lr, li;
        zoh_lambda(Lre, Lim, log_step, p, lr, li);
        float den = Lre[p] * Lre[p] + Lim[p] * Lim[p];
        float x = lr - 1.0f, y = li;
        float gr = (x * Lre[p] + y * Lim[p]) / den;
        float gi = (y * Lre[p] - x * Lim[p]) / den;
        float br = Bre[idx], bi = Bim[idx];
        Bcat[(size_t)p * 512 + h]         = f2h(gr * br - gi * bi);
        Bcat[(size_t)(512 + p) * 512 + h] = f2h(gr * bi + gi * br);
    } else if (b < 6144) {
        int idx = (b - 5120) * 256 + threadIdx.x;   // h*P + p
        int h = idx >> 9, p = idx & 511;
        size_t row = (size_t)h * 1024;
        Ccat[row + p]       = f2h(Cre[idx]);
        Ccat[row + 512 + p] = f2h(-Cim[idx]);
    } else {
        #pragma unroll
        for (int t = 0; t < 2; ++t) {
            int p = threadIdx.x + t * 256;
            float lr, li;
            zoh_lambda(Lre, Lim, log_step, p, lr, li);
            lbr[p] = lr; lbi[p] = li;
            float pr = 1.f, pi2 = 0.f;
            powr[p] = 1.f; powi[p] = 0.f;
            for (int k = 1; k <= T_CH; ++k) {
                float nr = pr * lr - pi2 * li;
                float ni = pr * li + pi2 * lr;
                pr = nr; pi2 = ni;
                powr[(size_t)k * P_DIM + p] = pr;
                powi[(size_t)k * P_DIM + p] = pi2;
            }
        }
    }
}

// ---------------------------------------------------------------------------
// Bu GEMM: 128x128 tile, BK=64, 4 waves, global_load_lds staging with
// XOR-swizzled source / ds_read pair. Writes Bu fp16 (re|im split at col 512)
// AND fused weighted chunk-sum partials from the fp32 accumulators
// (w_k = lambda_p^(31-k)).
// __launch_bounds__(256,2): 256-reg budget. (256,4) caps at 128 and SPILLS —
// round-3 regression: +183MB scratch writes/dispatch, GEMM 64->118us.
// ---------------------------------------------------------------------------
__global__ __launch_bounds__(256, 2) void gemm_bu(
    const u16* __restrict__ A0,
    const u16* __restrict__ Bmat,
    u16* __restrict__ O0, u16* __restrict__ O1,
    const float* __restrict__ powr, const float* __restrict__ powi,
    float* __restrict__ Rwr, float* __restrict__ Rwi,
    float* __restrict__ Iwr, float* __restrict__ Iwi)
{
    const int NBN = 8;
    __shared__ u16 Als[128 * 64];
    __shared__ u16 Bls[128 * 64];

    int b = blockIdx.x;
    int m = (b & 7) * 16 + b / (8 * NBN);
    int n = (b >> 3) & (NBN - 1);
    int m0 = m * 128, n0 = n * 128;

    int tid = threadIdx.x;
    int w = tid >> 6, lane = tid & 63;
    int wm = w >> 1, wn = w & 1;

    f32x4 acc[4][4];
    #pragma unroll
    for (int i = 0; i < 4; ++i)
        #pragma unroll
        for (int j = 0; j < 4; ++j) acc[i][j] = (f32x4)0.f;

    int lr8  = lane >> 3;
    int slin = lane & 7;

    char* AlsB = (char*)&Als[0];
    char* BlsB = (char*)&Bls[0];

    for (int k8 = 0; k8 < 8; ++k8) {
        int ko = k8 * 64;

        __syncthreads();
        #pragma unroll
        for (int c = 0; c < 4; ++c) {
            int sidx = w * 4 + c;
            int r = sidx * 8 + lr8;
            int g = slin ^ (r & 7);
            gload16(A0   + (size_t)(m0 + r) * 512 + ko + g * 8, AlsB + sidx * 1024);
            gload16(Bmat + (size_t)(n0 + r) * 512 + ko + g * 8, BlsB + sidx * 1024);
        }
        asm volatile("s_waitcnt vmcnt(0)" ::: "memory");
        __syncthreads();

        f16x8 a[4][2], bf[4][2];
        #pragma unroll
        for (int mm = 0; mm < 4; ++mm)
            #pragma unroll
            for (int kk = 0; kk < 2; ++kk) {
                int row = wm * 64 + mm * 16 + (lane & 15);
                int sl  = kk * 4 + (lane >> 4);
                int off = row * 128 + ((sl ^ (lane & 7)) << 4);
                a[mm][kk] = *(const f16x8*)(AlsB + off);
            }
        #pragma unroll
        for (int nn = 0; nn < 4; ++nn)
            #pragma unroll
            for (int kk = 0; kk < 2; ++kk) {
                int row = wn * 64 + nn * 16 + (lane & 15);
                int sl  = kk * 4 + (lane >> 4);
                int off = row * 128 + ((sl ^ (lane & 7)) << 4);
                bf[nn][kk] = *(const f16x8*)(BlsB + off);
            }
        #pragma unroll
        for (int mm = 0; mm < 4; ++mm)
            #pragma unroll
            for (int nn = 0; nn < 4; ++nn) {
                acc[mm][nn] = mfma_f16(a[mm][0], bf[nn][0], acc[mm][nn]);
                acc[mm][nn] = mfma_f16(a[mm][1], bf[nn][1], acc[mm][nn]);
            }
    }

    // epilogue: C/D layout col = lane&15, row = (lane>>4)*4 + reg  [m89]
    int colb = n0 + wn * 64;
    int rowb = m0 + wm * 64;
    #pragma unroll
    for (int mm = 0; mm < 4; ++mm)
        #pragma unroll
        for (int nn = 0; nn < 4; ++nn) {
            f32x4 v = acc[mm][nn];
            int col = colb + nn * 16 + (lane & 15);
            #pragma unroll
            for (int j = 0; j < 4; ++j) {
                int row = rowb + mm * 16 + (lane >> 4) * 4 + j;
                size_t oidx = (size_t)row * 512 + (col & 511);
                u16 hv = f2h(v[j]);
                if (col < 512) O0[oidx] = hv;
                else           O1[oidx] = hv;
            }
        }

    // fused weighted chunk sums (64 weight loads/lane; k depends on (mm&1,j))
    float swr[2][4] = {{0.f}};
    float swi[2][4] = {{0.f}};
    #pragma unroll
    for (int h = 0; h < 2; ++h)
        #pragma unroll
        for (int j = 0; j < 4; ++j) {
            int k = h * 16 + (lane >> 4) * 4 + j;    // 0..31
            int e = (T_CH - 1) - k;
            #pragma unroll
            for (int nn = 0; nn < 4; ++nn) {
                int p = (colb + nn * 16 + (lane & 15)) & 511;
                float wr = powr[(size_t)e * 512 + p];
                float wi = powi[(size_t)e * 512 + p];
                swr[0][nn] = fmaf(wr, acc[h][nn][j],     swr[0][nn]);
                swi[0][nn] = fmaf(wi, acc[h][nn][j],     swi[0][nn]);
                swr[1][nn] = fmaf(wr, acc[2 + h][nn][j], swr[1][nn]);
                swi[1][nn] = fmaf(wi, acc[2 + h][nn][j], swi[1][nn]);
            }
        }
    #pragma unroll
    for (int ch = 0; ch < 2; ++ch)
        #pragma unroll
        for (int nn = 0; nn < 4; ++nn) {
            float a2 = swr[ch][nn];
            a2 += __shfl_xor(a2, 16); a2 += __shfl_xor(a2, 32);
            swr[ch][nn] = a2;
            float b2 = swi[ch][nn];
            b2 += __shfl_xor(b2, 16); b2 += __shfl_xor(b2, 32);
            swi[ch][nn] = b2;
        }
    if (lane < 16) {
        #pragma unroll
        for (int ch = 0; ch < 2; ++ch) {
            int c = (m0 >> 5) + wm * 2 + ch;
            #pragma unroll
            for (int nn = 0; nn < 4; ++nn) {
                int col = colb + nn * 16 + lane;
                int p = col & 511;
                size_t pidx = (size_t)c * 512 + p;
                if (col < 512) { Rwr[pidx] = swr[ch][nn]; Rwi[pidx] = swi[ch][nn]; }
                else           { Iwr[pidx] = swr[ch][nn]; Iwi[pidx] = swi[ch][nn]; }
            }
        }
    }
}

// ---------------------------------------------------------------------------
// scan chunks: exclusive scan across 512 chunk aggregates with factor
// lambda^32, combining partials: s_re = Rwr - Iwi ; s_im = Rwi + Iwr.
// 8 blocks x 64 threads so L2 traffic isn't funneled through one CU.
// ---------------------------------------------------------------------------
__global__ __launch_bounds__(64) void scan_chunks(
    const float* __restrict__ Rwr, const float* __restrict__ Rwi,
    const float* __restrict__ Iwr, const float* __restrict__ Iwi,
    const float* __restrict__ powr, const float* __restrict__ powi,
    float* __restrict__ carr, float* __restrict__ cari)
{
    int p = blockIdx.x * 64 + threadIdx.x;
    float ar = powr[(size_t)T_CH * P_DIM + p];   // lambda^32
    float ai = powi[(size_t)T_CH * P_DIM + p];
    float sr = 0.f, si = 0.f;
    #pragma unroll 8
    for (int c = 0; c < NC; ++c) {
        size_t idx = (size_t)c * P_DIM + p;
        carr[idx] = sr; cari[idx] = si;
        float vre = Rwr[idx] - Iwi[idx];
        float vim = Rwi[idx] + Iwr[idx];
        float nr = fmaf(ar, sr, fmaf(-ai, si, vre));
        float ni = fmaf(ar, si, fmaf( ai, sr, vim));
        sr = nr; si = ni;
    }
}

// ---------------------------------------------------------------------------
// y GEMM with FUSED scan_fix: the A-operand x is computed on the fly from
// Bu + per-chunk carries (removes the 67MB x round-trip through HBM and one
// dispatch). K=1024 = [xr | xi] processed in PAIRS (q, q+8) so the complex
// recurrence per channel-group runs once: 256 threads = 4 chunks x 64
// channels, each a serial 32-step chain from carr/cari, results written fp16
// into the XOR-swizzled LDS A-tiles (ds_write_b16: 64 lanes x consecutive 2B
// = conflict-free). Both halves accumulate into the same acc (K-concat).
// out = acc + D[col]*uh. Numerically identical to scan_fix+gemm path.
// ---------------------------------------------------------------------------
__global__ __launch_bounds__(256, 2) void gemm_y_fused(
    const u16* __restrict__ burh, const u16* __restrict__ buih,
    const u16* __restrict__ Ccat,
    const float* __restrict__ lbr, const float* __restrict__ lbi,
    const float* __restrict__ carr, const float* __restrict__ cari,
    const float* __restrict__ Dvec, const u16* __restrict__ uIn,
    float* __restrict__ out)
{
    __shared__ u16 Axr[128 * 64];
    __shared__ u16 Axi[128 * 64];
    __shared__ u16 Bl0[128 * 64];
    __shared__ u16 Bl1[128 * 64];

    int b = blockIdx.x;
    int m = (b & 7) * 16 + b / 32;      // NBN=4
    int n = (b >> 3) & 3;
    int m0 = m * 128, n0 = n * 128;

    int tid = threadIdx.x;
    int w = tid >> 6, lane = tid & 63;
    int wm = w >> 1, wn = w & 1;

    f32x4 acc[4][4];
    #pragma unroll
    for (int i = 0; i < 4; ++i)
        #pragma unroll
        for (int j = 0; j < 4; ++j) acc[i][j] = (f32x4)0.f;

    int lr8  = lane >> 3;
    int slin = lane & 7;

    char* AxrB = (char*)&Axr[0];
    char* AxiB = (char*)&Axi[0];
    char* B0B  = (char*)&Bl0[0];
    char* B1B  = (char*)&Bl1[0];

    // x-compute mapping: wave = chunk, lane = channel-in-group
    int ch = w;                  // chunk 0..3 within tile
    int cglob = m * 4 + ch;      // global chunk

    for (int q = 0; q < 8; ++q) {
        int kB0 = q * 64;            // Ccat cols for xr half
        int kB1 = 512 + q * 64;      // Ccat cols for xi half

        __syncthreads();             // previous tiles fully consumed
        #pragma unroll
        for (int c = 0; c < 4; ++c) {
            int sidx = w * 4 + c;
            int r = sidx * 8 + lr8;
            int g = slin ^ (r & 7);
            gload16(Ccat + (size_t)(n0 + r) * 1024 + kB0 + g * 8, B0B + sidx * 1024);
            gload16(Ccat + (size_t)(n0 + r) * 1024 + kB1 + g * 8, B1B + sidx * 1024);
        }

        // compute x for channels p = q*64+lane, 32 rows of this wave's chunk
        {
            int p = q * 64 + lane;
            float lr_ = lbr[p], li_ = lbi[p];
            float xr = carr[(size_t)cglob * 512 + p];
            float xi = cari[(size_t)cglob * 512 + p];
            size_t gbase = (size_t)(m0 + ch * 32) * 512 + p;
            int rloc = ch * 32;
            int gsel = lane >> 3;            // granule of this channel
            int boff = (lane & 7) * 2;       // byte within granule
            #pragma unroll 4
            for (int k = 0; k < 32; ++k) {
                float br = h2f(burh[gbase + (size_t)k * 512]);
                float bi = h2f(buih[gbase + (size_t)k * 512]);
                float nr = fmaf(lr_, xr, fmaf(-li_, xi, br));
                float ni = fmaf(lr_, xi, fmaf( li_, xr, bi));
                xr = nr; xi = ni;
                int r = rloc + k;
                int off = r * 128 + ((gsel ^ (r & 7)) << 4) + boff;
                *(u16*)(AxrB + off) = f2h(nr);
                *(u16*)(AxiB + off) = f2h(ni);
            }
        }
        asm volatile("s_waitcnt vmcnt(0)" ::: "memory");
        __syncthreads();             // staged tiles visible

        // half 0: xr x Cre-part
        {
            f16x8 a[4][2], bf[4][2];
            #pragma unroll
            for (int mm = 0; mm < 4; ++mm)
                #pragma unroll
                for (int kk = 0; kk < 2; ++kk) {
                    int row = wm * 64 + mm * 16 + (lane & 15);
                    int sl  = kk * 4 + (lane >> 4);
                    int off = row * 128 + ((sl ^ (lane & 7)) << 4);
                    a[mm][kk] = *(const f16x8*)(AxrB + off);
                }
            #pragma unroll
            for (int nn = 0; nn < 4; ++nn)
                #pragma unroll
                for (int kk = 0; kk < 2; ++kk) {
                    int row = wn * 64 + nn * 16 + (lane & 15);
                    int sl  = kk * 4 + (lane >> 4);
                    int off = row * 128 + ((sl ^ (lane & 7)) << 4);
                    bf[nn][kk] = *(const f16x8*)(B0B + off);
                }
            #pragma unroll
            for (int mm = 0; mm < 4; ++mm)
                #pragma unroll
                for (int nn = 0; nn < 4; ++nn) {
                    acc[mm][nn] = mfma_f16(a[mm][0], bf[nn][0], acc[mm][nn]);
                    acc[mm][nn] = mfma_f16(a[mm][1], bf[nn][1], acc[mm][nn]);
                }
        }
        // half 1: xi x (-Cim)-part
        {
            f16x8 a[4][2], bf[4][2];
            #pragma unroll
            for (int mm = 0; mm < 4; ++mm)
                #pragma unroll
                for (int kk = 0; kk < 2; ++kk) {
                    int row = wm * 64 + mm * 16 + (lane & 15);
                    int sl  = kk * 4 + (lane >> 4);
                    int off = row * 128 + ((sl ^ (lane & 7)) << 4);
                    a[mm][kk] = *(const f16x8*)(AxiB + off);
                }
            #pragma unroll
            for (int nn = 0; nn < 4; ++nn)
                #pragma unroll
                for (int kk = 0; kk < 2; ++kk) {
                    int row = wn * 64 + nn * 16 + (lane & 15);
                    int sl  = kk * 4 + (lane >> 4);
                    int off = row * 128 + ((sl ^ (lane & 7)) << 4);
                    bf[nn][kk] = *(const f16x8*)(B1B + off);
                }
            #pragma unroll
            for (int mm = 0; mm < 4; ++mm)
                #pragma unroll
                for (int nn = 0; nn < 4; ++nn) {
                    acc[mm][nn] = mfma_f16(a[mm][0], bf[nn][0], acc[mm][nn]);
                    acc[mm][nn] = mfma_f16(a[mm][1], bf[nn][1], acc[mm][nn]);
                }
        }
    }

    // epilogue: out = acc + D*u
    int colb = n0 + wn * 64;
    int rowb = m0 + wm * 64;
    #pragma unroll
    for (int mm = 0; mm < 4; ++mm)
        #pragma unroll
        for (int nn = 0; nn < 4; ++nn) {
            f32x4 v = acc[mm][nn];
            int col = colb + nn * 16 + (lane & 15);
            #pragma unroll
            for (int j = 0; j < 4; ++j) {
                int row = rowb + mm * 16 + (lane >> 4) * 4 + j;
                size_t oidx = (size_t)row * 512 + col;
                out[oidx] = v[j] + Dvec[col] * h2f(uIn[oidx]);
            }
        }
}

// ---------------------------------------------------------------------------
extern "C" void kernel_launch(void* const* d_in, const int* in_sizes, int n_in,
                              void* d_out, int out_size, void* d_ws, size_t ws_size,
                              hipStream_t stream)
{
    const float* u        = (const float*)d_in[0];
    const float* Lre      = (const float*)d_in[1];
    const float* Lim      = (const float*)d_in[2];
    const float* Bre      = (const float*)d_in[3];
    const float* Bim      = (const float*)d_in[4];
    const float* Cre      = (const float*)d_in[5];
    const float* Cim      = (const float*)d_in[6];
    const float* D        = (const float*)d_in[7];
    const float* log_step = (const float*)d_in[8];
    float* out = (float*)d_out;

    // workspace layout (bytes)
    char* w8 = (char*)d_ws;
    u16*   burh = (u16*)(w8);                                // 16 MB
    u16*   buih = (u16*)(w8 + 16777216);                     // 16 MB
    u16*   uh   = (u16*)(w8 + 33554432);                     // 16 MB
    u16*   Bcat = (u16*)(w8 + 50331648);                     // 1 MB
    u16*   Ccat = (u16*)(w8 + 51380224);                     // 1 MB
    float* Rwr  = (float*)(w8 + 52428800);                   // 1 MB (NC*P fp32)
    float* Rwi  = (float*)(w8 + 53477376);
    float* Iwr  = (float*)(w8 + 54525952);
    float* Iwi  = (float*)(w8 + 55574528);
    float* carr = (float*)(w8 + 56623104);                   // 1 MB
    float* cari = (float*)(w8 + 57671680);
    float* powr = (float*)(w8 + 58720256);                   // 33*512*4
    float* powi = (float*)(w8 + 58787840);
    float* lbr  = (float*)(w8 + 58855424);                   // small
    float* lbi  = lbr + P_DIM;

    // one front dispatch: convert_u (4096 blk) + Bcat (1024) + Ccat (1024)
    // + lambda/power prep (1 blk)
    front_kernel<<<6145, 256, 0, stream>>>(
        u, Lre, Lim, log_step, Bre, Bim, Cre, Cim,
        uh, Bcat, Ccat, lbr, lbi, powr, powi);

    // Bu GEMM (+fused chunk-sum partials): A = uh, B = Bcat (1024 x 512)
    gemm_bu<<<1024, 256, 0, stream>>>(
        uh, Bcat, burh, buih, powr, powi, Rwr, Rwi, Iwr, Iwi);

    scan_chunks<<<8, 64, 0, stream>>>(Rwr, Rwi, Iwr, Iwi, powr, powi, carr, cari);

    // y GEMM with fused scan_fix: x computed in-kernel from Bu + carries
    gemm_y_fused<<<512, 256, 0, stream>>>(
        burh, buih, Ccat, lbr, lbi, carr, cari, D, uh, out);
}

// Round 10
// 112.761 us; speedup vs baseline: 1.1140x; 1.1119x over previous
//
#include <hip/hip_runtime.h>
#include <stdint.h>

#define L_DIM 16384
#define H_DIM 512
#define P_DIM 512
#define T_CH  32
#define NC    (L_DIM / T_CH)      // 512 chunks
#define LP    ((size_t)L_DIM * P_DIM)
#define LH    ((size_t)L_DIM * H_DIM)

typedef unsigned short u16;
typedef __attribute__((ext_vector_type(8))) _Float16 f16x8;  // 8 fp16 = 4 VGPRs
typedef __attribute__((ext_vector_type(4))) float f32x4;
typedef __attribute__((ext_vector_type(8))) unsigned short u16x8;

// ---- fp16 helpers ----------------------------------------------------------
__device__ __forceinline__ u16 f2h(float x) {
    _Float16 h = (_Float16)x;            // RTNE
    return __builtin_bit_cast(u16, h);
}
__device__ __forceinline__ float h2f(u16 h) {
    return (float)__builtin_bit_cast(_Float16, h);
}

// ---- async global->LDS, 16B per lane, wave-uniform LDS base ----------------
__device__ __forceinline__ void gload16(const void* g, void* lds) {
    __builtin_amdgcn_global_load_lds(
        (const __attribute__((address_space(1))) void*)g,
        (__attribute__((address_space(3))) void*)(uintptr_t)lds,
        16, 0, 0);
}

__device__ __forceinline__ f32x4 mfma_f16(f16x8 a, f16x8 b, f32x4 c) {
    return __builtin_amdgcn_mfma_f32_16x16x32_f16(a, b, c, 0, 0, 0);
}

// ---------------------------------------------------------------------------
// front kernel: one dispatch = convert_u + Bcat + Ccat + lambda/power prep.
// ---------------------------------------------------------------------------
__device__ __forceinline__ void zoh_lambda(
    const float* Lre, const float* Lim, const float* log_step, int p,
    float& lr, float& li)
{
    float st = expf(log_step[p]);
    float ar = Lre[p] * st, ai = Lim[p] * st;
    float er = expf(ar);
    lr = er * cosf(ai);
    li = er * sinf(ai);
}

__global__ __launch_bounds__(256) void front_kernel(
    const float* __restrict__ u,
    const float* __restrict__ Lre, const float* __restrict__ Lim,
    const float* __restrict__ log_step,
    const float* __restrict__ Bre, const float* __restrict__ Bim,
    const float* __restrict__ Cre, const float* __restrict__ Cim,
    u16* __restrict__ uh, u16* __restrict__ Bcat, u16* __restrict__ Ccat,
    float* __restrict__ lbr, float* __restrict__ lbi,
    float* __restrict__ powr, float* __restrict__ powi)
{
    int b = blockIdx.x;
    if (b < 4096) {
        size_t i = ((size_t)b * 256 + threadIdx.x) * 8;
        float4 v0 = *(const float4*)(u + i);
        float4 v1 = *(const float4*)(u + i + 4);
        u16x8 h;
        h[0] = f2h(v0.x); h[1] = f2h(v0.y); h[2] = f2h(v0.z); h[3] = f2h(v0.w);
        h[4] = f2h(v1.x); h[5] = f2h(v1.y); h[6] = f2h(v1.z); h[7] = f2h(v1.w);
        *(u16x8*)(uh + i) = h;
    } else if (b < 5120) {
        int idx = (b - 4096) * 256 + threadIdx.x;   // p*H + h
        int p = idx >> 9, h = idx & 511;
        float lr, li;
        zoh_lambda(Lre, Lim, log_step, p, lr, li);
        float den = Lre[p] * Lre[p] + Lim[p] * Lim[p];
        float x = lr - 1.0f, y = li;
        float gr = (x * Lre[p] + y * Lim[p]) / den;
        float gi = (y * Lre[p] - x * Lim[p]) / den;
        float br = Bre[idx], bi = Bim[idx];
        Bcat[(size_t)p * 512 + h]         = f2h(gr * br - gi * bi);
        Bcat[(size_t)(512 + p) * 512 + h] = f2h(gr * bi + gi * br);
    } else if (b < 6144) {
        int idx = (b - 5120) * 256 + threadIdx.x;   // h*P + p
        int h = idx >> 9, p = idx & 511;
        size_t row = (size_t)h * 1024;
        Ccat[row + p]       = f2h(Cre[idx]);
        Ccat[row + 512 + p] = f2h(-Cim[idx]);
    } else {
        #pragma unroll
        for (int t = 0; t < 2; ++t) {
            int p = threadIdx.x + t * 256;
            float lr, li;
            zoh_lambda(Lre, Lim, log_step, p, lr, li);
            lbr[p] = lr; lbi[p] = li;
            float pr = 1.f, pi2 = 0.f;
            powr[p] = 1.f; powi[p] = 0.f;
            for (int k = 1; k <= T_CH; ++k) {
                float nr = pr * lr - pi2 * li;
                float ni = pr * li + pi2 * lr;
                pr = nr; pi2 = ni;
                powr[(size_t)k * P_DIM + p] = pr;
                powi[(size_t)k * P_DIM + p] = pi2;
            }
        }
    }
}

// ---------------------------------------------------------------------------
// Bu GEMM: 128x128 tile, BK=64, 4 waves, global_load_lds staging with
// XOR-swizzled source / ds_read pair. Writes Bu fp16 (re|im split at col 512)
// AND fused weighted chunk-sum partials (w_k = lambda_p^(31-k)).
// Single-buffered on purpose: grid 1024 = 4 blocks/CU — implicit wave overlap
// covers the stage stall; 64KB dbuf would halve occupancy (m132-type loss).
// __launch_bounds__(256,2): 256-reg budget. (256,4) caps at 128 and SPILLS —
// round-3 regression: +183MB scratch writes/dispatch, GEMM 64->118us.
// ---------------------------------------------------------------------------
__global__ __launch_bounds__(256, 2) void gemm_bu(
    const u16* __restrict__ A0,
    const u16* __restrict__ Bmat,
    u16* __restrict__ O0, u16* __restrict__ O1,
    const float* __restrict__ powr, const float* __restrict__ powi,
    float* __restrict__ Rwr, float* __restrict__ Rwi,
    float* __restrict__ Iwr, float* __restrict__ Iwi)
{
    const int NBN = 8;
    __shared__ u16 Als[128 * 64];
    __shared__ u16 Bls[128 * 64];

    int b = blockIdx.x;
    int m = (b & 7) * 16 + b / (8 * NBN);
    int n = (b >> 3) & (NBN - 1);
    int m0 = m * 128, n0 = n * 128;

    int tid = threadIdx.x;
    int w = tid >> 6, lane = tid & 63;
    int wm = w >> 1, wn = w & 1;

    f32x4 acc[4][4];
    #pragma unroll
    for (int i = 0; i < 4; ++i)
        #pragma unroll
        for (int j = 0; j < 4; ++j) acc[i][j] = (f32x4)0.f;

    int lr8  = lane >> 3;
    int slin = lane & 7;

    char* AlsB = (char*)&Als[0];
    char* BlsB = (char*)&Bls[0];

    for (int k8 = 0; k8 < 8; ++k8) {
        int ko = k8 * 64;

        __syncthreads();
        #pragma unroll
        for (int c = 0; c < 4; ++c) {
            int sidx = w * 4 + c;
            int r = sidx * 8 + lr8;
            int g = slin ^ (r & 7);
            gload16(A0   + (size_t)(m0 + r) * 512 + ko + g * 8, AlsB + sidx * 1024);
            gload16(Bmat + (size_t)(n0 + r) * 512 + ko + g * 8, BlsB + sidx * 1024);
        }
        asm volatile("s_waitcnt vmcnt(0)" ::: "memory");
        __syncthreads();

        f16x8 a[4][2], bf[4][2];
        #pragma unroll
        for (int mm = 0; mm < 4; ++mm)
            #pragma unroll
            for (int kk = 0; kk < 2; ++kk) {
                int row = wm * 64 + mm * 16 + (lane & 15);
                int sl  = kk * 4 + (lane >> 4);
                int off = row * 128 + ((sl ^ (lane & 7)) << 4);
                a[mm][kk] = *(const f16x8*)(AlsB + off);
            }
        #pragma unroll
        for (int nn = 0; nn < 4; ++nn)
            #pragma unroll
            for (int kk = 0; kk < 2; ++kk) {
                int row = wn * 64 + nn * 16 + (lane & 15);
                int sl  = kk * 4 + (lane >> 4);
                int off = row * 128 + ((sl ^ (lane & 7)) << 4);
                bf[nn][kk] = *(const f16x8*)(BlsB + off);
            }
        #pragma unroll
        for (int mm = 0; mm < 4; ++mm)
            #pragma unroll
            for (int nn = 0; nn < 4; ++nn) {
                acc[mm][nn] = mfma_f16(a[mm][0], bf[nn][0], acc[mm][nn]);
                acc[mm][nn] = mfma_f16(a[mm][1], bf[nn][1], acc[mm][nn]);
            }
    }

    // epilogue: C/D layout col = lane&15, row = (lane>>4)*4 + reg  [m89]
    int colb = n0 + wn * 64;
    int rowb = m0 + wm * 64;
    #pragma unroll
    for (int mm = 0; mm < 4; ++mm)
        #pragma unroll
        for (int nn = 0; nn < 4; ++nn) {
            f32x4 v = acc[mm][nn];
            int col = colb + nn * 16 + (lane & 15);
            #pragma unroll
            for (int j = 0; j < 4; ++j) {
                int row = rowb + mm * 16 + (lane >> 4) * 4 + j;
                size_t oidx = (size_t)row * 512 + (col & 511);
                u16 hv = f2h(v[j]);
                if (col < 512) O0[oidx] = hv;
                else           O1[oidx] = hv;
            }
        }

    // fused weighted chunk sums (64 weight loads/lane; k depends on (mm&1,j))
    float swr[2][4] = {{0.f}};
    float swi[2][4] = {{0.f}};
    #pragma unroll
    for (int h = 0; h < 2; ++h)
        #pragma unroll
        for (int j = 0; j < 4; ++j) {
            int k = h * 16 + (lane >> 4) * 4 + j;    // 0..31
            int e = (T_CH - 1) - k;
            #pragma unroll
            for (int nn = 0; nn < 4; ++nn) {
                int p = (colb + nn * 16 + (lane & 15)) & 511;
                float wr = powr[(size_t)e * 512 + p];
                float wi = powi[(size_t)e * 512 + p];
                swr[0][nn] = fmaf(wr, acc[h][nn][j],     swr[0][nn]);
                swi[0][nn] = fmaf(wi, acc[h][nn][j],     swi[0][nn]);
                swr[1][nn] = fmaf(wr, acc[2 + h][nn][j], swr[1][nn]);
                swi[1][nn] = fmaf(wi, acc[2 + h][nn][j], swi[1][nn]);
            }
        }
    #pragma unroll
    for (int ch = 0; ch < 2; ++ch)
        #pragma unroll
        for (int nn = 0; nn < 4; ++nn) {
            float a2 = swr[ch][nn];
            a2 += __shfl_xor(a2, 16); a2 += __shfl_xor(a2, 32);
            swr[ch][nn] = a2;
            float b2 = swi[ch][nn];
            b2 += __shfl_xor(b2, 16); b2 += __shfl_xor(b2, 32);
            swi[ch][nn] = b2;
        }
    if (lane < 16) {
        #pragma unroll
        for (int ch = 0; ch < 2; ++ch) {
            int c = (m0 >> 5) + wm * 2 + ch;
            #pragma unroll
            for (int nn = 0; nn < 4; ++nn) {
                int col = colb + nn * 16 + lane;
                int p = col & 511;
                size_t pidx = (size_t)c * 512 + p;
                if (col < 512) { Rwr[pidx] = swr[ch][nn]; Rwi[pidx] = swi[ch][nn]; }
                else           { Iwr[pidx] = swr[ch][nn]; Iwi[pidx] = swi[ch][nn]; }
            }
        }
    }
}

// ---------------------------------------------------------------------------
// scan chunks: exclusive scan across 512 chunk aggregates with factor
// lambda^32, combining partials: s_re = Rwr - Iwi ; s_im = Rwi + Iwr.
// ---------------------------------------------------------------------------
__global__ __launch_bounds__(64) void scan_chunks(
    const float* __restrict__ Rwr, const float* __restrict__ Rwi,
    const float* __restrict__ Iwr, const float* __restrict__ Iwi,
    const float* __restrict__ powr, const float* __restrict__ powi,
    float* __restrict__ carr, float* __restrict__ cari)
{
    int p = blockIdx.x * 64 + threadIdx.x;
    float ar = powr[(size_t)T_CH * P_DIM + p];   // lambda^32
    float ai = powi[(size_t)T_CH * P_DIM + p];
    float sr = 0.f, si = 0.f;
    #pragma unroll 8
    for (int c = 0; c < NC; ++c) {
        size_t idx = (size_t)c * P_DIM + p;
        carr[idx] = sr; cari[idx] = si;
        float vre = Rwr[idx] - Iwi[idx];
        float vim = Rwi[idx] + Iwr[idx];
        float nr = fmaf(ar, sr, fmaf(-ai, si, vre));
        float ni = fmaf(ar, si, fmaf( ai, sr, vim));
        sr = nr; si = ni;
    }
}

// ---------------------------------------------------------------------------
// scan fix: local recurrence seeded with carry; emit x as fp16.
// Thread-per-(chunk,channel): 512 blocks x 512 threads = 16 waves/CU TLP.
// (Round-6 wave-per-chunk u16x8 variant was −12us: 2 waves/CU can't hide
// latency. Round-9 fusion into gemm_y was −12us: serial chain on the GEMM
// critical path at 2 blocks/CU. This shape is the measured best.)
// ---------------------------------------------------------------------------
__global__ __launch_bounds__(P_DIM) void scan_fix(
    const u16* __restrict__ burh, const u16* __restrict__ buih,
    const float* __restrict__ lbr, const float* __restrict__ lbi,
    const float* __restrict__ carr, const float* __restrict__ cari,
    u16* __restrict__ xrh, u16* __restrict__ xih)
{
    int p = threadIdx.x;
    int c = blockIdx.x;
    float lr = lbr[p], li = lbi[p];
    float xr = carr[(size_t)c * P_DIM + p];
    float xi = cari[(size_t)c * P_DIM + p];
    size_t base = (size_t)c * T_CH * P_DIM + p;
    #pragma unroll 4
    for (int k = 0; k < T_CH; ++k) {
        size_t idx = base + (size_t)k * P_DIM;
        float br = h2f(burh[idx]), bi = h2f(buih[idx]);
        float nr = fmaf(lr, xr, fmaf(-li, xi, br));
        float ni = fmaf(lr, xi, fmaf( li, xr, bi));
        xr = nr; xi = ni;
        xrh[idx] = f2h(xr);
        xih[idx] = f2h(xi);
    }
}

// ---------------------------------------------------------------------------
// y GEMM, double-buffered prefetch (T3/T4 minimum form): grid 512 = only
// 2 blocks/CU (grid-limited), so there is little implicit wave overlap and
// LDS headroom is free (64KB still fits 2 blocks) — the regime where explicit
// prefetch pays. Per tile kt: issue tile kt+1's 8 global_load_lds into buf^1,
// then s_waitcnt vmcnt(8) (tile kt done, kt+1 in flight) + RAW s_barrier
// (no compiler vmcnt(0) drain), ds_read+MFMA on buf, barrier.
// K=1024 = [xr | xi] segments. out = acc + D[col]*uh[row,col].
// ---------------------------------------------------------------------------
__global__ __launch_bounds__(256, 2) void gemm_y(
    const u16* __restrict__ A0, const u16* __restrict__ A1,
    const u16* __restrict__ Ccat,
    const float* __restrict__ Dvec, const u16* __restrict__ uIn,
    float* __restrict__ out)
{
    __shared__ u16 Als[2][128 * 64];
    __shared__ u16 Bls[2][128 * 64];

    int b = blockIdx.x;
    int m = (b & 7) * 16 + b / 32;      // NBN=4
    int n = (b >> 3) & 3;
    int m0 = m * 128, n0 = n * 128;

    int tid = threadIdx.x;
    int w = tid >> 6, lane = tid & 63;
    int wm = w >> 1, wn = w & 1;

    f32x4 acc[4][4];
    #pragma unroll
    for (int i = 0; i < 4; ++i)
        #pragma unroll
        for (int j = 0; j < 4; ++j) acc[i][j] = (f32x4)0.f;

    int lr8  = lane >> 3;
    int slin = lane & 7;

    auto stage = [&](int kt, int buf) {
        const u16* Ap = (kt < 8) ? A0 : A1;
        int ko = (kt & 7) * 64;
        int kB = kt * 64;
        char* Ad = (char*)&Als[buf][0];
        char* Bd = (char*)&Bls[buf][0];
        #pragma unroll
        for (int c = 0; c < 4; ++c) {
            int sidx = w * 4 + c;
            int r = sidx * 8 + lr8;
            int g = slin ^ (r & 7);
            gload16(Ap   + (size_t)(m0 + r) * 512  + ko + g * 8, Ad + sidx * 1024);
            gload16(Ccat + (size_t)(n0 + r) * 1024 + kB + g * 8, Bd + sidx * 1024);
        }
    };

    stage(0, 0);

    #pragma unroll
    for (int kt = 0; kt < 16; ++kt) {
        int cur = kt & 1;
        if (kt < 15) {
            stage(kt + 1, cur ^ 1);
            asm volatile("s_waitcnt vmcnt(8)" ::: "memory");
        } else {
            asm volatile("s_waitcnt vmcnt(0)" ::: "memory");
        }
        __builtin_amdgcn_s_barrier();
        __builtin_amdgcn_sched_barrier(0);

        char* AlsB = (char*)&Als[cur][0];
        char* BlsB = (char*)&Bls[cur][0];
        f16x8 a[4][2], bf[4][2];
        #pragma unroll
        for (int mm = 0; mm < 4; ++mm)
            #pragma unroll
            for (int kk = 0; kk < 2; ++kk) {
                int row = wm * 64 + mm * 16 + (lane & 15);
                int sl  = kk * 4 + (lane >> 4);
                int off = row * 128 + ((sl ^ (lane & 7)) << 4);
                a[mm][kk] = *(const f16x8*)(AlsB + off);
            }
        #pragma unroll
        for (int nn = 0; nn < 4; ++nn)
            #pragma unroll
            for (int kk = 0; kk < 2; ++kk) {
                int row = wn * 64 + nn * 16 + (lane & 15);
                int sl  = kk * 4 + (lane >> 4);
                int off = row * 128 + ((sl ^ (lane & 7)) << 4);
                bf[nn][kk] = *(const f16x8*)(BlsB + off);
            }
        #pragma unroll
        for (int mm = 0; mm < 4; ++mm)
            #pragma unroll
            for (int nn = 0; nn < 4; ++nn) {
                acc[mm][nn] = mfma_f16(a[mm][0], bf[nn][0], acc[mm][nn]);
                acc[mm][nn] = mfma_f16(a[mm][1], bf[nn][1], acc[mm][nn]);
            }

        __builtin_amdgcn_sched_barrier(0);
        __builtin_amdgcn_s_barrier();
    }

    // epilogue: out = acc + D*u
    int colb = n0 + wn * 64;
    int rowb = m0 + wm * 64;
    #pragma unroll
    for (int mm = 0; mm < 4; ++mm)
        #pragma unroll
        for (int nn = 0; nn < 4; ++nn) {
            f32x4 v = acc[mm][nn];
            int col = colb + nn * 16 + (lane & 15);
            #pragma unroll
            for (int j = 0; j < 4; ++j) {
                int row = rowb + mm * 16 + (lane >> 4) * 4 + j;
                size_t oidx = (size_t)row * 512 + col;
                out[oidx] = v[j] + Dvec[col] * h2f(uIn[oidx]);
            }
        }
}

// ---------------------------------------------------------------------------
extern "C" void kernel_launch(void* const* d_in, const int* in_sizes, int n_in,
                              void* d_out, int out_size, void* d_ws, size_t ws_size,
                              hipStream_t stream)
{
    const float* u        = (const float*)d_in[0];
    const float* Lre      = (const float*)d_in[1];
    const float* Lim      = (const float*)d_in[2];
    const float* Bre      = (const float*)d_in[3];
    const float* Bim      = (const float*)d_in[4];
    const float* Cre      = (const float*)d_in[5];
    const float* Cim      = (const float*)d_in[6];
    const float* D        = (const float*)d_in[7];
    const float* log_step = (const float*)d_in[8];
    float* out = (float*)d_out;

    // workspace layout (bytes)
    char* w8 = (char*)d_ws;
    u16*   burh = (u16*)(w8);                                // 16 MB
    u16*   buih = (u16*)(w8 + 16777216);                     // 16 MB
    u16*   xrh  = (u16*)(w8 + 33554432);                     // 16 MB
    u16*   xih  = (u16*)(w8 + 50331648);                     // 16 MB
    u16*   uh   = (u16*)(w8 + 67108864);                     // 16 MB
    u16*   Bcat = (u16*)(w8 + 83886080);                     // 1 MB
    u16*   Ccat = (u16*)(w8 + 84934656);                     // 1 MB
    float* Rwr  = (float*)(w8 + 85983232);                   // 1 MB (NC*P fp32)
    float* Rwi  = (float*)(w8 + 87031808);
    float* Iwr  = (float*)(w8 + 88080384);
    float* Iwi  = (float*)(w8 + 89128960);
    float* carr = (float*)(w8 + 90177536);                   // 1 MB
    float* cari = (float*)(w8 + 91226112);
    float* powr = (float*)(w8 + 92274688);                   // 33*512*4
    float* powi = (float*)(w8 + 92342272);
    float* lbr  = (float*)(w8 + 92409856);                   // small
    float* lbi  = lbr + P_DIM;

    // one front dispatch: convert_u (4096 blk) + Bcat (1024) + Ccat (1024)
    // + lambda/power prep (1 blk)
    front_kernel<<<6145, 256, 0, stream>>>(
        u, Lre, Lim, log_step, Bre, Bim, Cre, Cim,
        uh, Bcat, Ccat, lbr, lbi, powr, powi);

    // Bu GEMM (+fused chunk-sum partials): A = uh, B = Bcat (1024 x 512)
    gemm_bu<<<1024, 256, 0, stream>>>(
        uh, Bcat, burh, buih, powr, powi, Rwr, Rwi, Iwr, Iwi);

    scan_chunks<<<8, 64, 0, stream>>>(Rwr, Rwi, Iwr, Iwi, powr, powi, carr, cari);
    scan_fix<<<NC, P_DIM, 0, stream>>>(burh, buih, lbr, lbi, carr, cari, xrh, xih);

    // y GEMM (double-buffered prefetch): A segs [xr | xi], B = Ccat (512x1024)
    gemm_y<<<512, 256, 0, stream>>>(xrh, xih, Ccat, D, uh, out);
}

// Round 11
// 111.744 us; speedup vs baseline: 1.1242x; 1.0091x over previous
//
#include <hip/hip_runtime.h>
#include <stdint.h>

#define L_DIM 16384
#define H_DIM 512
#define P_DIM 512
#define T_CH  32
#define NC    (L_DIM / T_CH)      // 512 chunks
#define LP    ((size_t)L_DIM * P_DIM)
#define LH    ((size_t)L_DIM * H_DIM)

typedef unsigned short u16;
typedef __attribute__((ext_vector_type(8))) _Float16 f16x8;  // 8 fp16 = 4 VGPRs
typedef __attribute__((ext_vector_type(4))) float f32x4;
typedef __attribute__((ext_vector_type(8))) unsigned short u16x8;

// ---- fp16 helpers ----------------------------------------------------------
__device__ __forceinline__ u16 f2h(float x) {
    _Float16 h = (_Float16)x;            // RTNE
    return __builtin_bit_cast(u16, h);
}
__device__ __forceinline__ float h2f(u16 h) {
    return (float)__builtin_bit_cast(_Float16, h);
}

// ---- async global->LDS, 16B per lane, wave-uniform LDS base ----------------
__device__ __forceinline__ void gload16(const void* g, void* lds) {
    __builtin_amdgcn_global_load_lds(
        (const __attribute__((address_space(1))) void*)g,
        (__attribute__((address_space(3))) void*)(uintptr_t)lds,
        16, 0, 0);
}

__device__ __forceinline__ f32x4 mfma_f16(f16x8 a, f16x8 b, f32x4 c) {
    return __builtin_amdgcn_mfma_f32_16x16x32_f16(a, b, c, 0, 0, 0);
}

// ---------------------------------------------------------------------------
// front kernel: one dispatch = convert_u + Bcat + Ccat + lambda/power prep.
// ---------------------------------------------------------------------------
__device__ __forceinline__ void zoh_lambda(
    const float* Lre, const float* Lim, const float* log_step, int p,
    float& lr, float& li)
{
    float st = expf(log_step[p]);
    float ar = Lre[p] * st, ai = Lim[p] * st;
    float er = expf(ar);
    lr = er * cosf(ai);
    li = er * sinf(ai);
}

__global__ __launch_bounds__(256) void front_kernel(
    const float* __restrict__ u,
    const float* __restrict__ Lre, const float* __restrict__ Lim,
    const float* __restrict__ log_step,
    const float* __restrict__ Bre, const float* __restrict__ Bim,
    const float* __restrict__ Cre, const float* __restrict__ Cim,
    u16* __restrict__ uh, u16* __restrict__ Bcat, u16* __restrict__ Ccat,
    float* __restrict__ lbr, float* __restrict__ lbi,
    float* __restrict__ powr, float* __restrict__ powi)
{
    int b = blockIdx.x;
    if (b < 4096) {
        size_t i = ((size_t)b * 256 + threadIdx.x) * 8;
        float4 v0 = *(const float4*)(u + i);
        float4 v1 = *(const float4*)(u + i + 4);
        u16x8 h;
        h[0] = f2h(v0.x); h[1] = f2h(v0.y); h[2] = f2h(v0.z); h[3] = f2h(v0.w);
        h[4] = f2h(v1.x); h[5] = f2h(v1.y); h[6] = f2h(v1.z); h[7] = f2h(v1.w);
        *(u16x8*)(uh + i) = h;
    } else if (b < 5120) {
        int idx = (b - 4096) * 256 + threadIdx.x;   // p*H + h
        int p = idx >> 9, h = idx & 511;
        float lr, li;
        zoh_lambda(Lre, Lim, log_step, p, lr, li);
        float den = Lre[p] * Lre[p] + Lim[p] * Lim[p];
        float x = lr - 1.0f, y = li;
        float gr = (x * Lre[p] + y * Lim[p]) / den;
        float gi = (y * Lre[p] - x * Lim[p]) / den;
        float br = Bre[idx], bi = Bim[idx];
        Bcat[(size_t)p * 512 + h]         = f2h(gr * br - gi * bi);
        Bcat[(size_t)(512 + p) * 512 + h] = f2h(gr * bi + gi * br);
    } else if (b < 6144) {
        int idx = (b - 5120) * 256 + threadIdx.x;   // h*P + p
        int h = idx >> 9, p = idx & 511;
        size_t row = (size_t)h * 1024;
        Ccat[row + p]       = f2h(Cre[idx]);
        Ccat[row + 512 + p] = f2h(-Cim[idx]);
    } else {
        #pragma unroll
        for (int t = 0; t < 2; ++t) {
            int p = threadIdx.x + t * 256;
            float lr, li;
            zoh_lambda(Lre, Lim, log_step, p, lr, li);
            lbr[p] = lr; lbi[p] = li;
            float pr = 1.f, pi2 = 0.f;
            powr[p] = 1.f; powi[p] = 0.f;
            for (int k = 1; k <= T_CH; ++k) {
                float nr = pr * lr - pi2 * li;
                float ni = pr * li + pi2 * lr;
                pr = nr; pi2 = ni;
                powr[(size_t)k * P_DIM + p] = pr;
                powi[(size_t)k * P_DIM + p] = pi2;
            }
        }
    }
}

// ---------------------------------------------------------------------------
// Bu GEMM, double-buffered prefetch (same schedule that took gemm_y from
// ~750 to ~1000 TF in round 10): per k-tile issue next tile's 8
// global_load_lds into buf^1, s_waitcnt vmcnt(8) (current tile done, next in
// flight), RAW s_barrier (no compiler vmcnt(0) drain), ds_read+MFMA, barrier.
// 64KB LDS -> 2 blocks/CU; round-10 proved 2 blocks/CU suffices when the
// pipeline never drains. Writes Bu fp16 (re|im split at col 512) AND fused
// weighted chunk-sum partials (w_k = lambda_p^(31-k)).
// __launch_bounds__(256,2): 256-reg budget. (256,4) caps at 128 and SPILLS —
// round-3 regression: +183MB scratch writes/dispatch, GEMM 64->118us.
// ---------------------------------------------------------------------------
__global__ __launch_bounds__(256, 2) void gemm_bu(
    const u16* __restrict__ A0,
    const u16* __restrict__ Bmat,
    u16* __restrict__ O0, u16* __restrict__ O1,
    const float* __restrict__ powr, const float* __restrict__ powi,
    float* __restrict__ Rwr, float* __restrict__ Rwi,
    float* __restrict__ Iwr, float* __restrict__ Iwi)
{
    const int NBN = 8;
    __shared__ u16 Als[2][128 * 64];
    __shared__ u16 Bls[2][128 * 64];

    int b = blockIdx.x;
    int m = (b & 7) * 16 + b / (8 * NBN);
    int n = (b >> 3) & (NBN - 1);
    int m0 = m * 128, n0 = n * 128;

    int tid = threadIdx.x;
    int w = tid >> 6, lane = tid & 63;
    int wm = w >> 1, wn = w & 1;

    f32x4 acc[4][4];
    #pragma unroll
    for (int i = 0; i < 4; ++i)
        #pragma unroll
        for (int j = 0; j < 4; ++j) acc[i][j] = (f32x4)0.f;

    int lr8  = lane >> 3;
    int slin = lane & 7;

    auto stage = [&](int kt, int buf) {
        int ko = kt * 64;
        char* Ad = (char*)&Als[buf][0];
        char* Bd = (char*)&Bls[buf][0];
        #pragma unroll
        for (int c = 0; c < 4; ++c) {
            int sidx = w * 4 + c;
            int r = sidx * 8 + lr8;
            int g = slin ^ (r & 7);
            gload16(A0   + (size_t)(m0 + r) * 512 + ko + g * 8, Ad + sidx * 1024);
            gload16(Bmat + (size_t)(n0 + r) * 512 + ko + g * 8, Bd + sidx * 1024);
        }
    };

    stage(0, 0);

    #pragma unroll
    for (int kt = 0; kt < 8; ++kt) {
        int cur = kt & 1;
        if (kt < 7) {
            stage(kt + 1, cur ^ 1);
            asm volatile("s_waitcnt vmcnt(8)" ::: "memory");
        } else {
            asm volatile("s_waitcnt vmcnt(0)" ::: "memory");
        }
        __builtin_amdgcn_s_barrier();
        __builtin_amdgcn_sched_barrier(0);

        char* AlsB = (char*)&Als[cur][0];
        char* BlsB = (char*)&Bls[cur][0];
        f16x8 a[4][2], bf[4][2];
        #pragma unroll
        for (int mm = 0; mm < 4; ++mm)
            #pragma unroll
            for (int kk = 0; kk < 2; ++kk) {
                int row = wm * 64 + mm * 16 + (lane & 15);
                int sl  = kk * 4 + (lane >> 4);
                int off = row * 128 + ((sl ^ (lane & 7)) << 4);
                a[mm][kk] = *(const f16x8*)(AlsB + off);
            }
        #pragma unroll
        for (int nn = 0; nn < 4; ++nn)
            #pragma unroll
            for (int kk = 0; kk < 2; ++kk) {
                int row = wn * 64 + nn * 16 + (lane & 15);
                int sl  = kk * 4 + (lane >> 4);
                int off = row * 128 + ((sl ^ (lane & 7)) << 4);
                bf[nn][kk] = *(const f16x8*)(BlsB + off);
            }
        #pragma unroll
        for (int mm = 0; mm < 4; ++mm)
            #pragma unroll
            for (int nn = 0; nn < 4; ++nn) {
                acc[mm][nn] = mfma_f16(a[mm][0], bf[nn][0], acc[mm][nn]);
                acc[mm][nn] = mfma_f16(a[mm][1], bf[nn][1], acc[mm][nn]);
            }

        __builtin_amdgcn_sched_barrier(0);
        __builtin_amdgcn_s_barrier();
    }

    // epilogue: C/D layout col = lane&15, row = (lane>>4)*4 + reg  [m89]
    int colb = n0 + wn * 64;
    int rowb = m0 + wm * 64;
    #pragma unroll
    for (int mm = 0; mm < 4; ++mm)
        #pragma unroll
        for (int nn = 0; nn < 4; ++nn) {
            f32x4 v = acc[mm][nn];
            int col = colb + nn * 16 + (lane & 15);
            #pragma unroll
            for (int j = 0; j < 4; ++j) {
                int row = rowb + mm * 16 + (lane >> 4) * 4 + j;
                size_t oidx = (size_t)row * 512 + (col & 511);
                u16 hv = f2h(v[j]);
                if (col < 512) O0[oidx] = hv;
                else           O1[oidx] = hv;
            }
        }

    // fused weighted chunk sums (64 weight loads/lane; k depends on (mm&1,j))
    float swr[2][4] = {{0.f}};
    float swi[2][4] = {{0.f}};
    #pragma unroll
    for (int h = 0; h < 2; ++h)
        #pragma unroll
        for (int j = 0; j < 4; ++j) {
            int k = h * 16 + (lane >> 4) * 4 + j;    // 0..31
            int e = (T_CH - 1) - k;
            #pragma unroll
            for (int nn = 0; nn < 4; ++nn) {
                int p = (colb + nn * 16 + (lane & 15)) & 511;
                float wr = powr[(size_t)e * 512 + p];
                float wi = powi[(size_t)e * 512 + p];
                swr[0][nn] = fmaf(wr, acc[h][nn][j],     swr[0][nn]);
                swi[0][nn] = fmaf(wi, acc[h][nn][j],     swi[0][nn]);
                swr[1][nn] = fmaf(wr, acc[2 + h][nn][j], swr[1][nn]);
                swi[1][nn] = fmaf(wi, acc[2 + h][nn][j], swi[1][nn]);
            }
        }
    #pragma unroll
    for (int ch = 0; ch < 2; ++ch)
        #pragma unroll
        for (int nn = 0; nn < 4; ++nn) {
            float a2 = swr[ch][nn];
            a2 += __shfl_xor(a2, 16); a2 += __shfl_xor(a2, 32);
            swr[ch][nn] = a2;
            float b2 = swi[ch][nn];
            b2 += __shfl_xor(b2, 16); b2 += __shfl_xor(b2, 32);
            swi[ch][nn] = b2;
        }
    if (lane < 16) {
        #pragma unroll
        for (int ch = 0; ch < 2; ++ch) {
            int c = (m0 >> 5) + wm * 2 + ch;
            #pragma unroll
            for (int nn = 0; nn < 4; ++nn) {
                int col = colb + nn * 16 + lane;
                int p = col & 511;
                size_t pidx = (size_t)c * 512 + p;
                if (col < 512) { Rwr[pidx] = swr[ch][nn]; Rwi[pidx] = swi[ch][nn]; }
                else           { Iwr[pidx] = swr[ch][nn]; Iwi[pidx] = swi[ch][nn]; }
            }
        }
    }
}

// ---------------------------------------------------------------------------
// scan chunks: exclusive scan across 512 chunk aggregates with factor
// lambda^32, combining partials: s_re = Rwr - Iwi ; s_im = Rwi + Iwr.
// ---------------------------------------------------------------------------
__global__ __launch_bounds__(64) void scan_chunks(
    const float* __restrict__ Rwr, const float* __restrict__ Rwi,
    const float* __restrict__ Iwr, const float* __restrict__ Iwi,
    const float* __restrict__ powr, const float* __restrict__ powi,
    float* __restrict__ carr, float* __restrict__ cari)
{
    int p = blockIdx.x * 64 + threadIdx.x;
    float ar = powr[(size_t)T_CH * P_DIM + p];   // lambda^32
    float ai = powi[(size_t)T_CH * P_DIM + p];
    float sr = 0.f, si = 0.f;
    #pragma unroll 8
    for (int c = 0; c < NC; ++c) {
        size_t idx = (size_t)c * P_DIM + p;
        carr[idx] = sr; cari[idx] = si;
        float vre = Rwr[idx] - Iwi[idx];
        float vim = Rwi[idx] + Iwr[idx];
        float nr = fmaf(ar, sr, fmaf(-ai, si, vre));
        float ni = fmaf(ar, si, fmaf( ai, sr, vim));
        sr = nr; si = ni;
    }
}

// ---------------------------------------------------------------------------
// scan fix: local recurrence seeded with carry; emit x as fp16.
// Thread-per-(chunk,channel): 512 blocks x 512 threads = 16 waves/CU TLP.
// (Round-6 wave-per-chunk u16x8 variant was −12us: 2 waves/CU can't hide
// latency. Round-9 fusion into gemm_y was −12us: serial chain on the GEMM
// critical path at 2 blocks/CU. This shape is the measured best.)
// ---------------------------------------------------------------------------
__global__ __launch_bounds__(P_DIM) void scan_fix(
    const u16* __restrict__ burh, const u16* __restrict__ buih,
    const float* __restrict__ lbr, const float* __restrict__ lbi,
    const float* __restrict__ carr, const float* __restrict__ cari,
    u16* __restrict__ xrh, u16* __restrict__ xih)
{
    int p = threadIdx.x;
    int c = blockIdx.x;
    float lr = lbr[p], li = lbi[p];
    float xr = carr[(size_t)c * P_DIM + p];
    float xi = cari[(size_t)c * P_DIM + p];
    size_t base = (size_t)c * T_CH * P_DIM + p;
    #pragma unroll 4
    for (int k = 0; k < T_CH; ++k) {
        size_t idx = base + (size_t)k * P_DIM;
        float br = h2f(burh[idx]), bi = h2f(buih[idx]);
        float nr = fmaf(lr, xr, fmaf(-li, xi, br));
        float ni = fmaf(lr, xi, fmaf( li, xr, bi));
        xr = nr; xi = ni;
        xrh[idx] = f2h(xr);
        xih[idx] = f2h(xi);
    }
}

// ---------------------------------------------------------------------------
// y GEMM, double-buffered prefetch (T3/T4 minimum form). Round-10 measured:
// ~17us for 17.2 GF (~1000 TF effective, above the syncthreads-drain ceiling).
// K=1024 = [xr | xi] segments. out = acc + D[col]*uh[row,col].
// ---------------------------------------------------------------------------
__global__ __launch_bounds__(256, 2) void gemm_y(
    const u16* __restrict__ A0, const u16* __restrict__ A1,
    const u16* __restrict__ Ccat,
    const float* __restrict__ Dvec, const u16* __restrict__ uIn,
    float* __restrict__ out)
{
    __shared__ u16 Als[2][128 * 64];
    __shared__ u16 Bls[2][128 * 64];

    int b = blockIdx.x;
    int m = (b & 7) * 16 + b / 32;      // NBN=4
    int n = (b >> 3) & 3;
    int m0 = m * 128, n0 = n * 128;

    int tid = threadIdx.x;
    int w = tid >> 6, lane = tid & 63;
    int wm = w >> 1, wn = w & 1;

    f32x4 acc[4][4];
    #pragma unroll
    for (int i = 0; i < 4; ++i)
        #pragma unroll
        for (int j = 0; j < 4; ++j) acc[i][j] = (f32x4)0.f;

    int lr8  = lane >> 3;
    int slin = lane & 7;

    auto stage = [&](int kt, int buf) {
        const u16* Ap = (kt < 8) ? A0 : A1;
        int ko = (kt & 7) * 64;
        int kB = kt * 64;
        char* Ad = (char*)&Als[buf][0];
        char* Bd = (char*)&Bls[buf][0];
        #pragma unroll
        for (int c = 0; c < 4; ++c) {
            int sidx = w * 4 + c;
            int r = sidx * 8 + lr8;
            int g = slin ^ (r & 7);
            gload16(Ap   + (size_t)(m0 + r) * 512  + ko + g * 8, Ad + sidx * 1024);
            gload16(Ccat + (size_t)(n0 + r) * 1024 + kB + g * 8, Bd + sidx * 1024);
        }
    };

    stage(0, 0);

    #pragma unroll
    for (int kt = 0; kt < 16; ++kt) {
        int cur = kt & 1;
        if (kt < 15) {
            stage(kt + 1, cur ^ 1);
            asm volatile("s_waitcnt vmcnt(8)" ::: "memory");
        } else {
            asm volatile("s_waitcnt vmcnt(0)" ::: "memory");
        }
        __builtin_amdgcn_s_barrier();
        __builtin_amdgcn_sched_barrier(0);

        char* AlsB = (char*)&Als[cur][0];
        char* BlsB = (char*)&Bls[cur][0];
        f16x8 a[4][2], bf[4][2];
        #pragma unroll
        for (int mm = 0; mm < 4; ++mm)
            #pragma unroll
            for (int kk = 0; kk < 2; ++kk) {
                int row = wm * 64 + mm * 16 + (lane & 15);
                int sl  = kk * 4 + (lane >> 4);
                int off = row * 128 + ((sl ^ (lane & 7)) << 4);
                a[mm][kk] = *(const f16x8*)(AlsB + off);
            }
        #pragma unroll
        for (int nn = 0; nn < 4; ++nn)
            #pragma unroll
            for (int kk = 0; kk < 2; ++kk) {
                int row = wn * 64 + nn * 16 + (lane & 15);
                int sl  = kk * 4 + (lane >> 4);
                int off = row * 128 + ((sl ^ (lane & 7)) << 4);
                bf[nn][kk] = *(const f16x8*)(BlsB + off);
            }
        #pragma unroll
        for (int mm = 0; mm < 4; ++mm)
            #pragma unroll
            for (int nn = 0; nn < 4; ++nn) {
                acc[mm][nn] = mfma_f16(a[mm][0], bf[nn][0], acc[mm][nn]);
                acc[mm][nn] = mfma_f16(a[mm][1], bf[nn][1], acc[mm][nn]);
            }

        __builtin_amdgcn_sched_barrier(0);
        __builtin_amdgcn_s_barrier();
    }

    // epilogue: out = acc + D*u
    int colb = n0 + wn * 64;
    int rowb = m0 + wm * 64;
    #pragma unroll
    for (int mm = 0; mm < 4; ++mm)
        #pragma unroll
        for (int nn = 0; nn < 4; ++nn) {
            f32x4 v = acc[mm][nn];
            int col = colb + nn * 16 + (lane & 15);
            #pragma unroll
            for (int j = 0; j < 4; ++j) {
                int row = rowb + mm * 16 + (lane >> 4) * 4 + j;
                size_t oidx = (size_t)row * 512 + col;
                out[oidx] = v[j] + Dvec[col] * h2f(uIn[oidx]);
            }
        }
}

// ---------------------------------------------------------------------------
extern "C" void kernel_launch(void* const* d_in, const int* in_sizes, int n_in,
                              void* d_out, int out_size, void* d_ws, size_t ws_size,
                              hipStream_t stream)
{
    const float* u        = (const float*)d_in[0];
    const float* Lre      = (const float*)d_in[1];
    const float* Lim      = (const float*)d_in[2];
    const float* Bre      = (const float*)d_in[3];
    const float* Bim      = (const float*)d_in[4];
    const float* Cre      = (const float*)d_in[5];
    const float* Cim      = (const float*)d_in[6];
    const float* D        = (const float*)d_in[7];
    const float* log_step = (const float*)d_in[8];
    float* out = (float*)d_out;

    // workspace layout (bytes)
    char* w8 = (char*)d_ws;
    u16*   burh = (u16*)(w8);                                // 16 MB
    u16*   buih = (u16*)(w8 + 16777216);                     // 16 MB
    u16*   xrh  = (u16*)(w8 + 33554432);                     // 16 MB
    u16*   xih  = (u16*)(w8 + 50331648);                     // 16 MB
    u16*   uh   = (u16*)(w8 + 67108864);                     // 16 MB
    u16*   Bcat = (u16*)(w8 + 83886080);                     // 1 MB
    u16*   Ccat = (u16*)(w8 + 84934656);                     // 1 MB
    float* Rwr  = (float*)(w8 + 85983232);                   // 1 MB (NC*P fp32)
    float* Rwi  = (float*)(w8 + 87031808);
    float* Iwr  = (float*)(w8 + 88080384);
    float* Iwi  = (float*)(w8 + 89128960);
    float* carr = (float*)(w8 + 90177536);                   // 1 MB
    float* cari = (float*)(w8 + 91226112);
    float* powr = (float*)(w8 + 92274688);                   // 33*512*4
    float* powi = (float*)(w8 + 92342272);
    float* lbr  = (float*)(w8 + 92409856);                   // small
    float* lbi  = lbr + P_DIM;

    // one front dispatch: convert_u (4096 blk) + Bcat (1024) + Ccat (1024)
    // + lambda/power prep (1 blk)
    front_kernel<<<6145, 256, 0, stream>>>(
        u, Lre, Lim, log_step, Bre, Bim, Cre, Cim,
        uh, Bcat, Ccat, lbr, lbi, powr, powi);

    // Bu GEMM (+fused chunk-sum partials): A = uh, B = Bcat (1024 x 512)
    gemm_bu<<<1024, 256, 0, stream>>>(
        uh, Bcat, burh, buih, powr, powi, Rwr, Rwi, Iwr, Iwi);

    scan_chunks<<<8, 64, 0, stream>>>(Rwr, Rwi, Iwr, Iwi, powr, powi, carr, cari);
    scan_fix<<<NC, P_DIM, 0, stream>>>(burh, buih, lbr, lbi, carr, cari, xrh, xih);

    // y GEMM (double-buffered prefetch): A segs [xr | xi], B = Ccat (512x1024)
    gemm_y<<<512, 256, 0, stream>>>(xrh, xih, Ccat, D, uh, out);
}

// Round 12
// 105.950 us; speedup vs baseline: 1.1857x; 1.0547x over previous
//
#include <hip/hip_runtime.h>
#include <stdint.h>

#define L_DIM 16384
#define H_DIM 512
#define P_DIM 512
#define T_CH  32
#define NC    (L_DIM / T_CH)      // 512 chunks
#define LP    ((size_t)L_DIM * P_DIM)
#define LH    ((size_t)L_DIM * H_DIM)

typedef unsigned short u16;
typedef __attribute__((ext_vector_type(8))) _Float16 f16x8;  // 8 fp16 = 4 VGPRs
typedef __attribute__((ext_vector_type(4))) float f32x4;
typedef __attribute__((ext_vector_type(8))) unsigned short u16x8;

// ---- fp16 helpers ----------------------------------------------------------
__device__ __forceinline__ u16 f2h(float x) {
    _Float16 h = (_Float16)x;            // RTNE
    return __builtin_bit_cast(u16, h);
}
__device__ __forceinline__ float h2f(u16 h) {
    return (float)__builtin_bit_cast(_Float16, h);
}

// ---- async global->LDS, 16B per lane, wave-uniform LDS base ----------------
__device__ __forceinline__ void gload16(const void* g, void* lds) {
    __builtin_amdgcn_global_load_lds(
        (const __attribute__((address_space(1))) void*)g,
        (__attribute__((address_space(3))) void*)(uintptr_t)lds,
        16, 0, 0);
}

__device__ __forceinline__ f32x4 mfma_f16(f16x8 a, f16x8 b, f32x4 c) {
    return __builtin_amdgcn_mfma_f32_16x16x32_f16(a, b, c, 0, 0, 0);
}

// ---------------------------------------------------------------------------
// LAYOUT NOTE (round 12): re/im are INTERLEAVED along the channel axis
// everywhere. GEMMs are invariant to a K-permutation, so:
//   Bcat row 2p = Re(gamma*B)[p], row 2p+1 = Im(gamma*B)[p]  (1024 x 512)
//   Bu[row][2p]=re, [2p+1]=im  -> one u32 per (row,channel)
//   Ccat[h][2p]=Cre, [2p+1]=-Cim  (512 x 1024, K-interleaved)
//   x[row][2p]=xr, [2p+1]=xi   -> one u32 per (row,channel)
// This gives gemm_bu both parts of each channel in ONE block (final chunk
// sums computed locally) and halves scan_fix's VMEM instruction count.
// ---------------------------------------------------------------------------

// ---------------------------------------------------------------------------
// front kernel: one dispatch = convert_u + Bcat + Ccat + lambda/power prep.
// ---------------------------------------------------------------------------
__device__ __forceinline__ void zoh_lambda(
    const float* Lre, const float* Lim, const float* log_step, int p,
    float& lr, float& li)
{
    float st = expf(log_step[p]);
    float ar = Lre[p] * st, ai = Lim[p] * st;
    float er = expf(ar);
    lr = er * cosf(ai);
    li = er * sinf(ai);
}

__global__ __launch_bounds__(256) void front_kernel(
    const float* __restrict__ u,
    const float* __restrict__ Lre, const float* __restrict__ Lim,
    const float* __restrict__ log_step,
    const float* __restrict__ Bre, const float* __restrict__ Bim,
    const float* __restrict__ Cre, const float* __restrict__ Cim,
    u16* __restrict__ uh, u16* __restrict__ Bcat, u16* __restrict__ Ccat,
    float* __restrict__ lbr, float* __restrict__ lbi,
    float* __restrict__ powr, float* __restrict__ powi)
{
    int b = blockIdx.x;
    if (b < 4096) {
        size_t i = ((size_t)b * 256 + threadIdx.x) * 8;
        float4 v0 = *(const float4*)(u + i);
        float4 v1 = *(const float4*)(u + i + 4);
        u16x8 h;
        h[0] = f2h(v0.x); h[1] = f2h(v0.y); h[2] = f2h(v0.z); h[3] = f2h(v0.w);
        h[4] = f2h(v1.x); h[5] = f2h(v1.y); h[6] = f2h(v1.z); h[7] = f2h(v1.w);
        *(u16x8*)(uh + i) = h;
    } else if (b < 5120) {
        int idx = (b - 4096) * 256 + threadIdx.x;   // p*H + h
        int p = idx >> 9, h = idx & 511;
        float lr, li;
        zoh_lambda(Lre, Lim, log_step, p, lr, li);
        float den = Lre[p] * Lre[p] + Lim[p] * Lim[p];
        float x = lr - 1.0f, y = li;
        float gr = (x * Lre[p] + y * Lim[p]) / den;
        float gi = (y * Lre[p] - x * Lim[p]) / den;
        float br = Bre[idx], bi = Bim[idx];
        Bcat[(size_t)(2 * p) * 512 + h]     = f2h(gr * br - gi * bi);
        Bcat[(size_t)(2 * p + 1) * 512 + h] = f2h(gr * bi + gi * br);
    } else if (b < 6144) {
        int idx = (b - 5120) * 256 + threadIdx.x;   // h*P + p
        int h = idx >> 9, p = idx & 511;
        uint32_t pk = (uint32_t)f2h(Cre[idx]) | ((uint32_t)f2h(-Cim[idx]) << 16);
        *(uint32_t*)(Ccat + (size_t)h * 1024 + 2 * p) = pk;
    } else {
        #pragma unroll
        for (int t = 0; t < 2; ++t) {
            int p = threadIdx.x + t * 256;
            float lr, li;
            zoh_lambda(Lre, Lim, log_step, p, lr, li);
            lbr[p] = lr; lbi[p] = li;
            float pr = 1.f, pi2 = 0.f;
            powr[p] = 1.f; powi[p] = 0.f;
            for (int k = 1; k <= T_CH; ++k) {
                float nr = pr * lr - pi2 * li;
                float ni = pr * li + pi2 * lr;
                pr = nr; pi2 = ni;
                powr[(size_t)k * P_DIM + p] = pr;
                powi[(size_t)k * P_DIM + p] = pi2;
            }
        }
    }
}

// ---------------------------------------------------------------------------
// Bu GEMM, double-buffered prefetch. B = Bcat (1024 rows, re/im interleaved):
// output col 2p+sel = (sel ? im : re) of channel p. Writes interleaved Bu
// (u16 at row*1024+col) AND the FINAL per-chunk weighted sums (both parts of
// each channel live in this block): s(c,p) = sum_k lambda_p^(31-k)*Bu[k][p],
// via parity weights + shfl_xor(1) pair-reduce, stored interleaved in scf.
// __launch_bounds__(256,2): 256-reg budget. (256,4) caps at 128 and SPILLS —
// round-3 regression: +183MB scratch writes/dispatch, GEMM 64->118us.
// ---------------------------------------------------------------------------
__global__ __launch_bounds__(256, 2) void gemm_bu(
    const u16* __restrict__ A0,
    const u16* __restrict__ Bmat,
    u16* __restrict__ Ou,
    const float* __restrict__ powr, const float* __restrict__ powi,
    float* __restrict__ scf)
{
    const int NBN = 8;
    __shared__ u16 Als[2][128 * 64];
    __shared__ u16 Bls[2][128 * 64];

    int b = blockIdx.x;
    int m = (b & 7) * 16 + b / (8 * NBN);
    int n = (b >> 3) & (NBN - 1);
    int m0 = m * 128, n0 = n * 128;

    int tid = threadIdx.x;
    int w = tid >> 6, lane = tid & 63;
    int wm = w >> 1, wn = w & 1;

    f32x4 acc[4][4];
    #pragma unroll
    for (int i = 0; i < 4; ++i)
        #pragma unroll
        for (int j = 0; j < 4; ++j) acc[i][j] = (f32x4)0.f;

    int lr8  = lane >> 3;
    int slin = lane & 7;

    auto stage = [&](int kt, int buf) {
        int ko = kt * 64;
        char* Ad = (char*)&Als[buf][0];
        char* Bd = (char*)&Bls[buf][0];
        #pragma unroll
        for (int c = 0; c < 4; ++c) {
            int sidx = w * 4 + c;
            int r = sidx * 8 + lr8;
            int g = slin ^ (r & 7);
            gload16(A0   + (size_t)(m0 + r) * 512 + ko + g * 8, Ad + sidx * 1024);
            gload16(Bmat + (size_t)(n0 + r) * 512 + ko + g * 8, Bd + sidx * 1024);
        }
    };

    stage(0, 0);

    #pragma unroll
    for (int kt = 0; kt < 8; ++kt) {
        int cur = kt & 1;
        if (kt < 7) {
            stage(kt + 1, cur ^ 1);
            asm volatile("s_waitcnt vmcnt(8)" ::: "memory");
        } else {
            asm volatile("s_waitcnt vmcnt(0)" ::: "memory");
        }
        __builtin_amdgcn_s_barrier();
        __builtin_amdgcn_sched_barrier(0);

        char* AlsB = (char*)&Als[cur][0];
        char* BlsB = (char*)&Bls[cur][0];
        f16x8 a[4][2], bf[4][2];
        #pragma unroll
        for (int mm = 0; mm < 4; ++mm)
            #pragma unroll
            for (int kk = 0; kk < 2; ++kk) {
                int row = wm * 64 + mm * 16 + (lane & 15);
                int sl  = kk * 4 + (lane >> 4);
                int off = row * 128 + ((sl ^ (lane & 7)) << 4);
                a[mm][kk] = *(const f16x8*)(AlsB + off);
            }
        #pragma unroll
        for (int nn = 0; nn < 4; ++nn)
            #pragma unroll
            for (int kk = 0; kk < 2; ++kk) {
                int row = wn * 64 + nn * 16 + (lane & 15);
                int sl  = kk * 4 + (lane >> 4);
                int off = row * 128 + ((sl ^ (lane & 7)) << 4);
                bf[nn][kk] = *(const f16x8*)(BlsB + off);
            }
        #pragma unroll
        for (int mm = 0; mm < 4; ++mm)
            #pragma unroll
            for (int nn = 0; nn < 4; ++nn) {
                acc[mm][nn] = mfma_f16(a[mm][0], bf[nn][0], acc[mm][nn]);
                acc[mm][nn] = mfma_f16(a[mm][1], bf[nn][1], acc[mm][nn]);
            }

        __builtin_amdgcn_sched_barrier(0);
        __builtin_amdgcn_s_barrier();
    }

    // epilogue: C/D layout col = lane&15, row = (lane>>4)*4 + reg  [m89]
    // col here is the interleaved index 2p+sel -> direct store into Ou.
    int colb = n0 + wn * 64;
    int rowb = m0 + wm * 64;
    #pragma unroll
    for (int mm = 0; mm < 4; ++mm)
        #pragma unroll
        for (int nn = 0; nn < 4; ++nn) {
            f32x4 v = acc[mm][nn];
            int col = colb + nn * 16 + (lane & 15);
            #pragma unroll
            for (int j = 0; j < 4; ++j) {
                int row = rowb + mm * 16 + (lane >> 4) * 4 + j;
                Ou[(size_t)row * 1024 + col] = f2h(v[j]);
            }
        }

    // fused weighted chunk sums with parity weights:
    //   even col (re part): +wr -> s_re, +wi -> s_im
    //   odd  col (im part): -wi -> s_re, +wr -> s_im
    float s1[2][4] = {{0.f}};   // -> s_re
    float s2[2][4] = {{0.f}};   // -> s_im
    #pragma unroll
    for (int h = 0; h < 2; ++h)
        #pragma unroll
        for (int j = 0; j < 4; ++j) {
            int k = h * 16 + (lane >> 4) * 4 + j;    // 0..31
            int e = (T_CH - 1) - k;
            #pragma unroll
            for (int nn = 0; nn < 4; ++nn) {
                int col = colb + nn * 16 + (lane & 15);
                int p = col >> 1, sel = col & 1;
                float wr = powr[(size_t)e * 512 + p];
                float wi = powi[(size_t)e * 512 + p];
                float w1 = sel ? -wi : wr;
                float w2 = sel ?  wr : wi;
                s1[0][nn] = fmaf(w1, acc[h][nn][j],     s1[0][nn]);
                s2[0][nn] = fmaf(w2, acc[h][nn][j],     s2[0][nn]);
                s1[1][nn] = fmaf(w1, acc[2 + h][nn][j], s1[1][nn]);
                s2[1][nn] = fmaf(w2, acc[2 + h][nn][j], s2[1][nn]);
            }
        }
    #pragma unroll
    for (int ch = 0; ch < 2; ++ch)
        #pragma unroll
        for (int nn = 0; nn < 4; ++nn) {
            float a2 = s1[ch][nn];
            a2 += __shfl_xor(a2, 1); a2 += __shfl_xor(a2, 16); a2 += __shfl_xor(a2, 32);
            s1[ch][nn] = a2;
            float b2 = s2[ch][nn];
            b2 += __shfl_xor(b2, 1); b2 += __shfl_xor(b2, 16); b2 += __shfl_xor(b2, 32);
            s2[ch][nn] = b2;
        }
    if (lane < 16) {
        #pragma unroll
        for (int ch = 0; ch < 2; ++ch) {
            int c = (m0 >> 5) + wm * 2 + ch;
            #pragma unroll
            for (int nn = 0; nn < 4; ++nn) {
                int col = colb + nn * 16 + lane;     // interleaved index
                scf[(size_t)c * 1024 + col] = (col & 1) ? s2[ch][nn] : s1[ch][nn];
            }
        }
    }
}

// ---------------------------------------------------------------------------
// scan chunks: exclusive scan across 512 chunk aggregates with factor
// lambda^32. scf/carrci are (c, p) float2-interleaved.
// ---------------------------------------------------------------------------
__global__ __launch_bounds__(64) void scan_chunks(
    const float* __restrict__ scf,
    const float* __restrict__ powr, const float* __restrict__ powi,
    float* __restrict__ carrci)
{
    int p = blockIdx.x * 64 + threadIdx.x;
    float ar = powr[(size_t)T_CH * P_DIM + p];   // lambda^32
    float ai = powi[(size_t)T_CH * P_DIM + p];
    float sr = 0.f, si = 0.f;
    #pragma unroll 8
    for (int c = 0; c < NC; ++c) {
        size_t idx = ((size_t)c * 512 + p) * 2;
        float2 cv; cv.x = sr; cv.y = si;
        *(float2*)(carrci + idx) = cv;
        float2 sv = *(const float2*)(scf + idx);
        float nr = fmaf(ar, sr, fmaf(-ai, si, sv.x));
        float ni = fmaf(ar, si, fmaf( ai, sr, sv.y));
        sr = nr; si = ni;
    }
}

// ---------------------------------------------------------------------------
// scan fix: local recurrence seeded with carry; emit x as packed fp16 pairs.
// Thread-per-(chunk,channel), 512x512 = 16 waves/CU TLP (measured best shape;
// round-6 64-thr version and round-9 gemm fusion were both −12us).
// Interleaved layout: 1 u32 load + 1 u32 store per step (was 2+2 x 2B).
// ---------------------------------------------------------------------------
__global__ __launch_bounds__(P_DIM) void scan_fix(
    const uint32_t* __restrict__ buc,
    const float* __restrict__ lbr, const float* __restrict__ lbi,
    const float* __restrict__ carrci,
    uint32_t* __restrict__ xc)
{
    int p = threadIdx.x;
    int c = blockIdx.x;
    float lr = lbr[p], li = lbi[p];
    float2 cv = *(const float2*)(carrci + ((size_t)c * 512 + p) * 2);
    float xr = cv.x, xi = cv.y;
    size_t base = (size_t)c * T_CH * 512 + p;
    #pragma unroll 8
    for (int k = 0; k < T_CH; ++k) {
        size_t idx = base + (size_t)k * 512;
        uint32_t bv = buc[idx];
        float br = h2f((u16)(bv & 0xffffu));
        float bi = h2f((u16)(bv >> 16));
        float nr = fmaf(lr, xr, fmaf(-li, xi, br));
        float ni = fmaf(lr, xi, fmaf( li, xr, bi));
        xr = nr; xi = ni;
        xc[idx] = (uint32_t)f2h(nr) | ((uint32_t)f2h(ni) << 16);
    }
}

// ---------------------------------------------------------------------------
// y GEMM, double-buffered prefetch (round-10: ~1000 TF effective). A = x
// (L x 1024, K-interleaved), B = Ccat (512 x 1024, same K-interleave — GEMM
// is invariant to the K permutation). out = acc + D[col]*uh[row,col].
// ---------------------------------------------------------------------------
__global__ __launch_bounds__(256, 2) void gemm_y(
    const u16* __restrict__ Ax,
    const u16* __restrict__ Ccat,
    const float* __restrict__ Dvec, const u16* __restrict__ uIn,
    float* __restrict__ out)
{
    __shared__ u16 Als[2][128 * 64];
    __shared__ u16 Bls[2][128 * 64];

    int b = blockIdx.x;
    int m = (b & 7) * 16 + b / 32;      // NBN=4
    int n = (b >> 3) & 3;
    int m0 = m * 128, n0 = n * 128;

    int tid = threadIdx.x;
    int w = tid >> 6, lane = tid & 63;
    int wm = w >> 1, wn = w & 1;

    f32x4 acc[4][4];
    #pragma unroll
    for (int i = 0; i < 4; ++i)
        #pragma unroll
        for (int j = 0; j < 4; ++j) acc[i][j] = (f32x4)0.f;

    int lr8  = lane >> 3;
    int slin = lane & 7;

    auto stage = [&](int kt, int buf) {
        int kB = kt * 64;
        char* Ad = (char*)&Als[buf][0];
        char* Bd = (char*)&Bls[buf][0];
        #pragma unroll
        for (int c = 0; c < 4; ++c) {
            int sidx = w * 4 + c;
            int r = sidx * 8 + lr8;
            int g = slin ^ (r & 7);
            gload16(Ax   + (size_t)(m0 + r) * 1024 + kB + g * 8, Ad + sidx * 1024);
            gload16(Ccat + (size_t)(n0 + r) * 1024 + kB + g * 8, Bd + sidx * 1024);
        }
    };

    stage(0, 0);

    #pragma unroll
    for (int kt = 0; kt < 16; ++kt) {
        int cur = kt & 1;
        if (kt < 15) {
            stage(kt + 1, cur ^ 1);
            asm volatile("s_waitcnt vmcnt(8)" ::: "memory");
        } else {
            asm volatile("s_waitcnt vmcnt(0)" ::: "memory");
        }
        __builtin_amdgcn_s_barrier();
        __builtin_amdgcn_sched_barrier(0);

        char* AlsB = (char*)&Als[cur][0];
        char* BlsB = (char*)&Bls[cur][0];
        f16x8 a[4][2], bf[4][2];
        #pragma unroll
        for (int mm = 0; mm < 4; ++mm)
            #pragma unroll
            for (int kk = 0; kk < 2; ++kk) {
                int row = wm * 64 + mm * 16 + (lane & 15);
                int sl  = kk * 4 + (lane >> 4);
                int off = row * 128 + ((sl ^ (lane & 7)) << 4);
                a[mm][kk] = *(const f16x8*)(AlsB + off);
            }
        #pragma unroll
        for (int nn = 0; nn < 4; ++nn)
            #pragma unroll
            for (int kk = 0; kk < 2; ++kk) {
                int row = wn * 64 + nn * 16 + (lane & 15);
                int sl  = kk * 4 + (lane >> 4);
                int off = row * 128 + ((sl ^ (lane & 7)) << 4);
                bf[nn][kk] = *(const f16x8*)(BlsB + off);
            }
        #pragma unroll
        for (int mm = 0; mm < 4; ++mm)
            #pragma unroll
            for (int nn = 0; nn < 4; ++nn) {
                acc[mm][nn] = mfma_f16(a[mm][0], bf[nn][0], acc[mm][nn]);
                acc[mm][nn] = mfma_f16(a[mm][1], bf[nn][1], acc[mm][nn]);
            }

        __builtin_amdgcn_sched_barrier(0);
        __builtin_amdgcn_s_barrier();
    }

    // epilogue: out = acc + D*u
    int colb = n0 + wn * 64;
    int rowb = m0 + wm * 64;
    #pragma unroll
    for (int mm = 0; mm < 4; ++mm)
        #pragma unroll
        for (int nn = 0; nn < 4; ++nn) {
            f32x4 v = acc[mm][nn];
            int col = colb + nn * 16 + (lane & 15);
            #pragma unroll
            for (int j = 0; j < 4; ++j) {
                int row = rowb + mm * 16 + (lane >> 4) * 4 + j;
                size_t oidx = (size_t)row * 512 + col;
                out[oidx] = v[j] + Dvec[col] * h2f(uIn[oidx]);
            }
        }
}

// ---------------------------------------------------------------------------
extern "C" void kernel_launch(void* const* d_in, const int* in_sizes, int n_in,
                              void* d_out, int out_size, void* d_ws, size_t ws_size,
                              hipStream_t stream)
{
    const float* u        = (const float*)d_in[0];
    const float* Lre      = (const float*)d_in[1];
    const float* Lim      = (const float*)d_in[2];
    const float* Bre      = (const float*)d_in[3];
    const float* Bim      = (const float*)d_in[4];
    const float* Cre      = (const float*)d_in[5];
    const float* Cim      = (const float*)d_in[6];
    const float* D        = (const float*)d_in[7];
    const float* log_step = (const float*)d_in[8];
    float* out = (float*)d_out;

    // workspace layout (bytes)
    char* w8 = (char*)d_ws;
    u16*      buc  = (u16*)(w8);                             // 33.5 MB (L x 1024, interleaved)
    u16*      xc   = (u16*)(w8 + 33554432);                  // 33.5 MB (L x 1024, interleaved)
    u16*      uh   = (u16*)(w8 + 67108864);                  // 16.8 MB
    u16*      Bcat = (u16*)(w8 + 83886080);                  // 1 MB
    u16*      Ccat = (u16*)(w8 + 84934656);                  // 1 MB
    float*    scf  = (float*)(w8 + 85983232);                // 2 MB (NC x 512 float2)
    float*    carrci = (float*)(w8 + 88080384);              // 2 MB
    float*    powr = (float*)(w8 + 90177536);                // 33*512*4
    float*    powi = (float*)(w8 + 90245120);
    float*    lbr  = (float*)(w8 + 90312704);                // small
    float*    lbi  = lbr + P_DIM;

    // one front dispatch: convert_u (4096 blk) + Bcat (1024) + Ccat (1024)
    // + lambda/power prep (1 blk)
    front_kernel<<<6145, 256, 0, stream>>>(
        u, Lre, Lim, log_step, Bre, Bim, Cre, Cim,
        uh, Bcat, Ccat, lbr, lbi, powr, powi);

    // Bu GEMM (+fused final chunk sums): A = uh, B = Bcat (1024 x 512)
    gemm_bu<<<1024, 256, 0, stream>>>(
        uh, Bcat, buc, powr, powi, scf);

    scan_chunks<<<8, 64, 0, stream>>>(scf, powr, powi, carrci);
    scan_fix<<<NC, P_DIM, 0, stream>>>((const uint32_t*)buc, lbr, lbi, carrci, (uint32_t*)xc);

    // y GEMM (double-buffered prefetch): A = xc (K-interleaved), B = Ccat
    gemm_y<<<512, 256, 0, stream>>>(xc, Ccat, D, uh, out);
}